// Round 4
// baseline (573.943 us; speedup 1.0000x reference)
//
#include <hip/hip_runtime.h>

#define DD 128
#define HH 8
#define DFF 512
#define EPS 1e-6f
#define SLOPE 0.2f
#define TM 64

typedef float f32x4 __attribute__((ext_vector_type(4)));
typedef short bf16x8 __attribute__((ext_vector_type(8)));

__device__ __forceinline__ ushort f2bf(float f) {
    unsigned u = __float_as_uint(f);
    return (ushort)((u + 0x7FFFu + ((u >> 16) & 1u)) >> 16);   // RNE
}
__device__ __forceinline__ float bf2f(ushort h) {
    return __uint_as_float(((unsigned)h) << 16);
}

// ---------------- zero int buffer ----------------
__global__ void kzero(int* __restrict__ p, int n) {
    int i = blockIdx.x * blockDim.x + threadIdx.x;
    if (i < n) p[i] = 0;
}

// ---------------- prep: transpose + split fp32 -> bf16 hi/lo ----------------
// src [R][C] fp32  ->  hi/lo [C][R] bf16 (row stride R)
__global__ void ksplitT(const float* __restrict__ src, ushort* __restrict__ hi,
                        ushort* __restrict__ lo, int R, int C) {
    __shared__ float tile[32][33];
    const int tc = blockIdx.x * 32, tr = blockIdx.y * 32;
    const int lx = threadIdx.x, ly = threadIdx.y;      // 32 x 8
    for (int i = 0; i < 32; i += 8) {
        int r = tr + ly + i, c = tc + lx;
        tile[ly + i][lx] = (r < R && c < C) ? src[(size_t)r * C + c] : 0.f;
    }
    __syncthreads();
    for (int i = 0; i < 32; i += 8) {
        int c = tc + ly + i, r = tr + lx;
        if (c < C && r < R) {
            float f = tile[lx][ly + i];
            ushort h = f2bf(f);
            hi[(size_t)c * R + r] = h;
            lo[(size_t)c * R + r] = f2bf(f - bf2f(h));
        }
    }
}

// ---------------- prep: attention weight fold ----------------
__global__ void kattw(const float* __restrict__ W, const float* __restrict__ asrc,
                      const float* __restrict__ adst, ushort* __restrict__ hi,
                      ushort* __restrict__ lo) {
    const int k = threadIdx.x;   // 128 threads
    for (int h = 0; h < HH; ++h) {
        float s1 = 0.f, s2 = 0.f;
        #pragma unroll
        for (int dh = 0; dh < 16; ++dh) {
            float w = W[k * DD + h * 16 + dh];
            s1 = fmaf(w, asrc[h * 16 + dh], s1);
            s2 = fmaf(w, adst[h * 16 + dh], s2);
        }
        ushort h1 = f2bf(s1);
        hi[(128 + h) * DD + k] = h1;
        lo[(128 + h) * DD + k] = f2bf(s1 - bf2f(h1));
        ushort h2 = f2bf(s2);
        hi[(136 + h) * DD + k] = h2;
        lo[(136 + h) * DD + k] = f2bf(s2 - bf2f(h2));
    }
}

// ---------------- K1: LN1 + [x | a_s | a_d] = ln1 @ [W_att | Was | Wad] via MFMA ----------------
__global__ __launch_bounds__(256) void k1_mfma(
    const float* __restrict__ nf, const float* __restrict__ g, const float* __restrict__ b,
    const ushort* __restrict__ WAhi, const ushort* __restrict__ WAlo,
    float* __restrict__ x, float* __restrict__ a_s, float* __restrict__ a_d, int n) {
    const int tid = threadIdx.x;
    const int w = tid >> 6, l = tid & 63;
    const int l15 = l & 15, l4 = l >> 4;
    const int nbase = blockIdx.x * TM;
    int arow = nbase + w * 16 + l15;
    if (arow >= n) arow = n - 1;

    float v[4][8];
    const float* ap = nf + (size_t)arow * DD + l4 * 8;
    #pragma unroll
    for (int s = 0; s < 4; ++s) {
        *(float4*)&v[s][0] = *(const float4*)(ap + s * 32);
        *(float4*)&v[s][4] = *(const float4*)(ap + s * 32 + 4);
    }
    float sum = 0.f;
    #pragma unroll
    for (int s = 0; s < 4; ++s)
        #pragma unroll
        for (int j = 0; j < 8; ++j) sum += v[s][j];
    sum += __shfl_xor(sum, 16);
    sum += __shfl_xor(sum, 32);
    const float mean = sum * (1.f / DD);
    float qs = 0.f;
    #pragma unroll
    for (int s = 0; s < 4; ++s)
        #pragma unroll
        for (int j = 0; j < 8; ++j) { float d = v[s][j] - mean; qs += d * d; }
    qs += __shfl_xor(qs, 16);
    qs += __shfl_xor(qs, 32);
    const float iv = 1.f / (sqrtf(qs * (1.f / (DD - 1))) + EPS);

    bf16x8 Ahi[4], Alo[4];
    #pragma unroll
    for (int s = 0; s < 4; ++s) {
        const int k0 = s * 32 + l4 * 8;
        float gv[8], bv[8];
        *(float4*)&gv[0] = *(const float4*)(g + k0);
        *(float4*)&gv[4] = *(const float4*)(g + k0 + 4);
        *(float4*)&bv[0] = *(const float4*)(b + k0);
        *(float4*)&bv[4] = *(const float4*)(b + k0 + 4);
        bf16x8 hv, lv;
        #pragma unroll
        for (int j = 0; j < 8; ++j) {
            float f = fmaf(gv[j], (v[s][j] - mean) * iv, bv[j]);
            ushort hb = f2bf(f);
            hv[j] = (short)hb;
            lv[j] = (short)f2bf(f - bf2f(hb));
        }
        Ahi[s] = hv; Alo[s] = lv;
    }

    #pragma unroll
    for (int oc = 0; oc < 9; ++oc) {
        f32x4 acc = (f32x4){0.f, 0.f, 0.f, 0.f};
        const ushort* bp = WAhi + (size_t)(oc * 16 + l15) * DD + l4 * 8;
        const ushort* lp = WAlo + (size_t)(oc * 16 + l15) * DD + l4 * 8;
        #pragma unroll
        for (int s = 0; s < 4; ++s) {
            bf16x8 bh = *(const bf16x8*)(bp + s * 32);
            bf16x8 bl = *(const bf16x8*)(lp + s * 32);
            acc = __builtin_amdgcn_mfma_f32_16x16x32_bf16(Ahi[s], bh, acc, 0, 0, 0);
            acc = __builtin_amdgcn_mfma_f32_16x16x32_bf16(Alo[s], bh, acc, 0, 0, 0);
            acc = __builtin_amdgcn_mfma_f32_16x16x32_bf16(Ahi[s], bl, acc, 0, 0, 0);
        }
        #pragma unroll
        for (int i = 0; i < 4; ++i) {
            const int node = nbase + w * 16 + l4 * 4 + i;
            if (node < n) {
                if (oc < 8) x[(size_t)node * DD + oc * 16 + l15] = acc[i];
                else if (l15 < 8) a_s[node * HH + l15] = acc[i];
                else a_d[node * HH + (l15 - 8)] = acc[i];
            }
        }
    }
}

// ---------------- K2: in-degree count ----------------
__global__ void k2_deg(const int* __restrict__ ei, int* __restrict__ deg, int E) {
    int e = blockIdx.x * blockDim.x + threadIdx.x;
    if (e < E) atomicAdd(&deg[ei[E + e]], 1);
}

// ---------------- K3a/b/c: hierarchical exclusive scan ----------------
__global__ __launch_bounds__(1024) void k3a(const int* __restrict__ deg, int* __restrict__ incl,
                                            int* __restrict__ bsum, int n) {
    __shared__ int wsum[16];
    const int b = blockIdx.x, t = threadIdx.x;
    const int i0 = b * 4096 + t * 4;
    int4 v = make_int4(0, 0, 0, 0);
    if (i0 + 3 < n) v = *(const int4*)&deg[i0];
    else {
        int* vp = (int*)&v;
        for (int q = 0; q < 4; ++q) vp[q] = (i0 + q < n) ? deg[i0 + q] : 0;
    }
    const int s1 = v.x, s2 = s1 + v.y, s3 = s2 + v.z, s4 = s3 + v.w;
    const int lane = t & 63, wv = t >> 6;
    int xx = s4;
    #pragma unroll
    for (int off = 1; off < 64; off <<= 1) {
        int y = __shfl_up(xx, off);
        if (lane >= off) xx += y;
    }
    if (lane == 63) wsum[wv] = xx;
    __syncthreads();
    if (wv == 0) {
        int y = (lane < 16) ? wsum[lane] : 0;
        #pragma unroll
        for (int off = 1; off < 16; off <<= 1) {
            int z = __shfl_up(y, off);
            if (lane >= off) y += z;
        }
        if (lane < 16) wsum[lane] = y;
    }
    __syncthreads();
    const int wbase = (wv == 0) ? 0 : wsum[wv - 1];
    const int excl = xx - s4 + wbase;
    if (i0 < n) {
        int4 o = make_int4(excl + s1, excl + s2, excl + s3, excl + s4);
        if (i0 + 3 < n) *(int4*)&incl[i0] = o;
        else {
            int* op = (int*)&o;
            for (int q = 0; q < 4; ++q) if (i0 + q < n) incl[i0 + q] = op[q];
        }
    }
    if (t == 1023) bsum[b] = wbase + xx;
}

__global__ void k3b(int* __restrict__ bsum, int nb) {
    int t = threadIdx.x;
    int v = (t < nb) ? bsum[t] : 0;
    #pragma unroll
    for (int off = 1; off < 64; off <<= 1) {
        int y = __shfl_up(v, off);
        if (t >= off) v += y;
    }
    if (t < nb) bsum[t] = v;   // inclusive
}

__global__ void k3c(const int* __restrict__ incl, const int* __restrict__ bsum,
                    const int* __restrict__ deg, int* __restrict__ row_ptr,
                    int* __restrict__ cursor, int n) {
    int i = blockIdx.x * blockDim.x + threadIdx.x;
    if (i < n) {
        int b = i >> 12;
        int base = b ? bsum[b - 1] : 0;
        int inc = incl[i] + base;
        row_ptr[i + 1] = inc;
        cursor[i] = inc - deg[i];
        if (i == 0) row_ptr[0] = 0;
    }
}

// ---------------- K4: scatter src ids into CSR ----------------
__global__ void k4_scatter(const int* __restrict__ ei, int* __restrict__ cursor,
                           int* __restrict__ col_src, int E) {
    int e = blockIdx.x * blockDim.x + threadIdx.x;
    if (e < E) {
        int dst = ei[E + e];
        int pos = atomicAdd(&cursor[dst], 1);
        col_src[pos] = ei[e];
    }
}

// ---------------- K5: per-dst online-softmax gather + residual + LN2 ----------------
// Explicit next-batch double buffering: batch k+1 loads issue before batch k math.
__global__ __launch_bounds__(256) void k5_gather(
    const float* __restrict__ x, const float* __restrict__ a_s, const float* __restrict__ a_d,
    const int* __restrict__ row_ptr, const int* __restrict__ col_src,
    const float* __restrict__ nf, const float* __restrict__ bias_att,
    const float* __restrict__ ln2g, const float* __restrict__ ln2b,
    float* __restrict__ nf1, float* __restrict__ h2, int n) {
    const int w = (blockIdx.x * blockDim.x + threadIdx.x) >> 6;
    if (w >= n) return;
    const int lane = threadIdx.x & 63;
    const int h = lane >> 3;
    const int c0 = lane * 2;
    const float ad = a_d[w * HH + h];
    float e = a_s[w * HH + h] + ad;
    e = e > 0.f ? e : SLOPE * e;
    float m = e, denom = 1.f;
    float2 xv = *(const float2*)&x[(size_t)w * DD + c0];
    float acc0 = xv.x, acc1 = xv.y;
    const int beg = row_ptr[w], end = row_ptr[w + 1];
    int j = beg;
    const int j4end = beg + ((end - beg) & ~3);

#define BATCH_MATH(F0, F1, F2, F3, X0, X1, X2, X3) {                                   \
        float f0 = (F0) + ad, f1 = (F1) + ad, f2 = (F2) + ad, f3 = (F3) + ad;          \
        f0 = f0 > 0.f ? f0 : SLOPE * f0;  f1 = f1 > 0.f ? f1 : SLOPE * f1;             \
        f2 = f2 > 0.f ? f2 : SLOPE * f2;  f3 = f3 > 0.f ? f3 : SLOPE * f3;             \
        const float mb = fmaxf(fmaxf(f0, f1), fmaxf(f2, f3));                          \
        const float nm = fmaxf(m, mb);                                                 \
        const float sc = __expf(m - nm);                                               \
        const float p0 = __expf(f0 - nm), p1 = __expf(f1 - nm);                        \
        const float p2 = __expf(f2 - nm), p3 = __expf(f3 - nm);                        \
        denom = denom * sc + ((p0 + p1) + (p2 + p3));                                  \
        acc0 = acc0 * sc + (fmaf(X0.x, p0, X1.x * p1) + fmaf(X2.x, p2, X3.x * p3));    \
        acc1 = acc1 * sc + (fmaf(X0.y, p0, X1.y * p1) + fmaf(X2.y, p2, X3.y * p3));    \
        m = nm; }

    if (j < j4end) {
        // prologue: load batch 0
        int s0 = col_src[j], s1 = col_src[j + 1], s2 = col_src[j + 2], s3 = col_src[j + 3];
        float e0 = a_s[s0 * HH + h], e1 = a_s[s1 * HH + h];
        float e2 = a_s[s2 * HH + h], e3 = a_s[s3 * HH + h];
        float2 x0 = *(const float2*)&x[(size_t)s0 * DD + c0];
        float2 x1 = *(const float2*)&x[(size_t)s1 * DD + c0];
        float2 x2 = *(const float2*)&x[(size_t)s2 * DD + c0];
        float2 x3 = *(const float2*)&x[(size_t)s3 * DD + c0];
        for (j += 4;; j += 4) {
            const bool more = j < j4end;
            float ne0, ne1, ne2, ne3;
            float2 nx0, nx1, nx2, nx3;
            if (more) {   // issue next-batch loads before current-batch math
                const int t0 = col_src[j], t1 = col_src[j + 1];
                const int t2 = col_src[j + 2], t3 = col_src[j + 3];
                ne0 = a_s[t0 * HH + h]; ne1 = a_s[t1 * HH + h];
                ne2 = a_s[t2 * HH + h]; ne3 = a_s[t3 * HH + h];
                nx0 = *(const float2*)&x[(size_t)t0 * DD + c0];
                nx1 = *(const float2*)&x[(size_t)t1 * DD + c0];
                nx2 = *(const float2*)&x[(size_t)t2 * DD + c0];
                nx3 = *(const float2*)&x[(size_t)t3 * DD + c0];
            }
            BATCH_MATH(e0, e1, e2, e3, x0, x1, x2, x3)
            if (!more) break;
            e0 = ne0; e1 = ne1; e2 = ne2; e3 = ne3;
            x0 = nx0; x1 = nx1; x2 = nx2; x3 = nx3;
        }
    }
    for (; j < end; ++j) {
        const int s0 = col_src[j];
        float ev = a_s[s0 * HH + h] + ad;
        ev = ev > 0.f ? ev : SLOPE * ev;
        const float2 x0 = *(const float2*)&x[(size_t)s0 * DD + c0];
        const float nm = fmaxf(m, ev);
        const float sc = __expf(m - nm);
        const float pp = __expf(ev - nm);
        denom = denom * sc + pp;
        acc0 = acc0 * sc + x0.x * pp;
        acc1 = acc1 * sc + x0.y * pp;
        m = nm;
    }
#undef BATCH_MATH
    const float inv = 1.f / (denom + 1e-16f);
    float o0 = acc0 * inv + bias_att[c0]     + nf[(size_t)w * DD + c0];
    float o1 = acc1 * inv + bias_att[c0 + 1] + nf[(size_t)w * DD + c0 + 1];
    *(float2*)&nf1[(size_t)w * DD + c0] = make_float2(o0, o1);
    float s = o0 + o1;
    #pragma unroll
    for (int o = 32; o >= 1; o >>= 1) s += __shfl_xor(s, o);
    const float mean = s * (1.f / DD);
    const float d0 = o0 - mean, d1 = o1 - mean;
    float q = d0 * d0 + d1 * d1;
    #pragma unroll
    for (int o = 32; o >= 1; o >>= 1) q += __shfl_xor(q, o);
    const float var = q * (1.f / (DD - 1));
    const float iv = 1.f / (sqrtf(var) + EPS);
    float z0 = ln2g[c0] * d0 * iv + ln2b[c0];
    float z1 = ln2g[c0 + 1] * d1 * iv + ln2b[c0 + 1];
    *(float2*)&h2[(size_t)w * DD + c0] = make_float2(z0, z1);
}

// ---------------- K6: split-bf16 MFMA FFN, LDS-free for W, barrier-free ----------------
// B-frags stream from L2 (weights ~320KB, fully cached). Only LDS: wave-private
// 4KB hh transpose buffer -> zero __syncthreads in the whole kernel.
__global__ __launch_bounds__(256, 4) void k6_mfma(
    const float* __restrict__ h2, const float* __restrict__ nf1,
    const ushort* __restrict__ W1Thi, const ushort* __restrict__ W1Tlo,
    const ushort* __restrict__ W2Thi, const ushort* __restrict__ W2Tlo,
    const float* __restrict__ b1, const float* __restrict__ b2,
    float* __restrict__ out, int n) {
    __shared__ float hhs[4096];                     // 16KB: 4 waves x [16 nodes][64 ff]
    const int tid = threadIdx.x;
    const int w = tid >> 6, l = tid & 63;
    const int l15 = l & 15, l4 = l >> 4;
    const int nbase = blockIdx.x * TM;
    char* hw = (char*)hhs + w * 4096;               // wave-private region

    int arow = nbase + w * 16 + l15;
    if (arow >= n) arow = n - 1;                    // clamp; tail writes guarded
    const float* ap = h2 + (size_t)arow * DD + l4 * 8;
    bf16x8 Ahi[4], Alo[4];
    #pragma unroll
    for (int s = 0; s < 4; ++s) {
        float v[8];
        *(float4*)&v[0] = *(const float4*)(ap + s * 32);
        *(float4*)&v[4] = *(const float4*)(ap + s * 32 + 4);
        bf16x8 hv, lv;
        #pragma unroll
        for (int jj = 0; jj < 8; ++jj) {
            ushort hb = f2bf(v[jj]);
            hv[jj] = (short)hb;
            lv[jj] = (short)f2bf(v[jj] - bf2f(hb));
        }
        Ahi[s] = hv; Alo[s] = lv;
    }

    f32x4 acc_o[8];
    #pragma unroll
    for (int oc = 0; oc < 8; ++oc) acc_o[oc] = (f32x4){0.f, 0.f, 0.f, 0.f};

    for (int ch = 0; ch < 8; ++ch) {
        // ---- stage A: hh[16 nodes][64 ff] = relu(h2 @ W1_chunk + b1), B-frags from L2
        #pragma unroll
        for (int tc = 0; tc < 4; ++tc) {
            f32x4 a = (f32x4){0.f, 0.f, 0.f, 0.f};
            const ushort* bp = W1Thi + (size_t)(ch * 64 + tc * 16 + l15) * DD + l4 * 8;
            const ushort* lp = W1Tlo + (size_t)(ch * 64 + tc * 16 + l15) * DD + l4 * 8;
            #pragma unroll
            for (int s = 0; s < 4; ++s) {
                bf16x8 bh = *(const bf16x8*)(bp + s * 32);
                bf16x8 bl = *(const bf16x8*)(lp + s * 32);
                a = __builtin_amdgcn_mfma_f32_16x16x32_bf16(Ahi[s], bh, a, 0, 0, 0);
                a = __builtin_amdgcn_mfma_f32_16x16x32_bf16(Alo[s], bh, a, 0, 0, 0);
                a = __builtin_amdgcn_mfma_f32_16x16x32_bf16(Ahi[s], bl, a, 0, 0, 0);
            }
            const float bias = b1[ch * 64 + tc * 16 + l15];
            #pragma unroll
            for (int i = 0; i < 4; ++i) {
                float hvv = fmaxf(a[i] + bias, 0.f);
                const int row = l4 * 4 + i;                      // 0..15 within wave tile
                const int byte = (row * 256 + (tc * 16 + l15) * 4) ^ ((row & 7) << 4);
                *(float*)(hw + byte) = hvv;
            }
        }
        // ---- transpose read-back (same wave: lgkmcnt ordering, no barrier)
        bf16x8 Phi[2], Plo[2];
        #pragma unroll
        for (int cs = 0; cs < 2; ++cs) {
            const int row = l15;
            const int base = row * 256 + (cs * 32 + l4 * 8) * 4;
            const int msk = (row & 7) << 4;
            float v[8];
            *(float4*)&v[0] = *(const float4*)(hw + (base ^ msk));
            *(float4*)&v[4] = *(const float4*)(hw + ((base + 16) ^ msk));
            bf16x8 hv, lv;
            #pragma unroll
            for (int jj = 0; jj < 8; ++jj) {
                ushort hb = f2bf(v[jj]);
                hv[jj] = (short)hb;
                lv[jj] = (short)f2bf(v[jj] - bf2f(hb));
            }
            Phi[cs] = hv; Plo[cs] = lv;
        }
        // ---- stage B: acc_o += hh @ W2_chunk, B-frags from L2
        #pragma unroll
        for (int oc = 0; oc < 8; ++oc) {
            #pragma unroll
            for (int cs = 0; cs < 2; ++cs) {
                const ushort* bp = W2Thi + (size_t)(oc * 16 + l15) * DFF + ch * 64 + cs * 32 + l4 * 8;
                const ushort* lp = W2Tlo + (size_t)(oc * 16 + l15) * DFF + ch * 64 + cs * 32 + l4 * 8;
                bf16x8 bh = *(const bf16x8*)bp;
                bf16x8 bl = *(const bf16x8*)lp;
                acc_o[oc] = __builtin_amdgcn_mfma_f32_16x16x32_bf16(Phi[cs], bh, acc_o[oc], 0, 0, 0);
                acc_o[oc] = __builtin_amdgcn_mfma_f32_16x16x32_bf16(Plo[cs], bh, acc_o[oc], 0, 0, 0);
                acc_o[oc] = __builtin_amdgcn_mfma_f32_16x16x32_bf16(Phi[cs], bl, acc_o[oc], 0, 0, 0);
            }
        }
    }
    // ---- epilogue: + b2 + residual
    #pragma unroll
    for (int oc = 0; oc < 8; ++oc) {
        const int col = oc * 16 + l15;
        const float b2v = b2[col];
        #pragma unroll
        for (int i = 0; i < 4; ++i) {
            const int node = nbase + w * 16 + l4 * 4 + i;
            if (node < n)
                out[(size_t)node * DD + col] = acc_o[oc][i] + b2v + nf1[(size_t)node * DD + col];
        }
    }
}

extern "C" void kernel_launch(void* const* d_in, const int* in_sizes, int n_in,
                              void* d_out, int out_size, void* d_ws, size_t ws_size,
                              hipStream_t stream) {
    const float* nf       = (const float*)d_in[0];
    const int*   ei       = (const int*)d_in[1];
    const float* ln1_g    = (const float*)d_in[2];
    const float* ln1_b    = (const float*)d_in[3];
    const float* W_att    = (const float*)d_in[4];
    const float* att_src  = (const float*)d_in[5];
    const float* att_dst  = (const float*)d_in[6];
    const float* bias_att = (const float*)d_in[7];
    const float* ln2_g    = (const float*)d_in[8];
    const float* ln2_b    = (const float*)d_in[9];
    const float* W1       = (const float*)d_in[10];
    const float* b1       = (const float*)d_in[11];
    const float* W2       = (const float*)d_in[12];
    const float* b2       = (const float*)d_in[13];
    const int n = in_sizes[0] / DD;
    const int E = in_sizes[1] / 2;

    char* ws = (char*)d_ws;
    size_t off = 0;
    auto alloc = [&](size_t bytes) {
        off = (off + 255) & ~(size_t)255;
        char* p = ws + off;
        off += bytes;
        return p;
    };
    float*  x       = (float*)alloc((size_t)n * DD * 4);
    float*  a_s     = (float*)alloc((size_t)n * HH * 4);
    float*  a_d     = (float*)alloc((size_t)n * HH * 4);
    float*  nf1     = (float*)alloc((size_t)n * DD * 4);
    float*  h2      = (float*)alloc((size_t)n * DD * 4);
    int*    row_ptr = (int*)alloc((size_t)(n + 1) * 4);
    int*    cursor  = (int*)alloc((size_t)n * 4);
    int*    deg     = (int*)alloc((size_t)n * 4);
    int*    incl    = (int*)alloc((size_t)n * 4);
    int*    bsum    = (int*)alloc(64 * 4);
    int*    col_src = (int*)alloc((size_t)E * 4);
    ushort* WAhi    = (ushort*)alloc((size_t)144 * DD * 2);   // [W_att^T | Was | Wad]
    ushort* WAlo    = (ushort*)alloc((size_t)144 * DD * 2);
    ushort* W1Thi   = (ushort*)alloc((size_t)DFF * DD * 2);
    ushort* W1Tlo   = (ushort*)alloc((size_t)DFF * DD * 2);
    ushort* W2Thi   = (ushort*)alloc((size_t)DD * DFF * 2);
    ushort* W2Tlo   = (ushort*)alloc((size_t)DD * DFF * 2);
    (void)ws_size; (void)n_in; (void)out_size;

    const int nb3 = (n + 4095) / 4096;

    ksplitT<<<dim3(DD / 32, DD / 32), dim3(32, 8), 0, stream>>>(W_att, WAhi, WAlo, DD, DD);
    kattw<<<1, 128, 0, stream>>>(W_att, att_src, att_dst, WAhi, WAlo);
    ksplitT<<<dim3(DFF / 32, DD / 32), dim3(32, 8), 0, stream>>>(W1, W1Thi, W1Tlo, DD, DFF);
    ksplitT<<<dim3(DD / 32, DFF / 32), dim3(32, 8), 0, stream>>>(W2, W2Thi, W2Tlo, DFF, DD);
    kzero<<<(n + 255) / 256, 256, 0, stream>>>(deg, n);
    k1_mfma<<<(n + TM - 1) / TM, 256, 0, stream>>>(nf, ln1_g, ln1_b, WAhi, WAlo, x, a_s, a_d, n);
    k2_deg<<<(E + 255) / 256, 256, 0, stream>>>(ei, deg, E);
    k3a<<<nb3, 1024, 0, stream>>>(deg, incl, bsum, n);
    k3b<<<1, 64, 0, stream>>>(bsum, nb3);
    k3c<<<(n + 255) / 256, 256, 0, stream>>>(incl, bsum, deg, row_ptr, cursor, n);
    k4_scatter<<<(E + 255) / 256, 256, 0, stream>>>(ei, cursor, col_src, E);
    k5_gather<<<(n + 3) / 4, 256, 0, stream>>>(x, a_s, a_d, row_ptr, col_src, nf, bias_att,
                                               ln2_g, ln2_b, nf1, h2, n);
    k6_mfma<<<(n + TM - 1) / TM, 256, 0, stream>>>(h2, nf1, W1Thi, W1Tlo, W2Thi, W2Tlo,
                                                   b1, b2, (float*)d_out, n);
}

// Round 5
// 402.625 us; speedup vs baseline: 1.4255x; 1.4255x over previous
//
#include <hip/hip_runtime.h>

#define DD 128
#define HH 8
#define DFF 512
#define EPS 1e-6f
#define SLOPE 0.2f
#define TM 64

typedef float f32x4 __attribute__((ext_vector_type(4)));
typedef short bf16x8 __attribute__((ext_vector_type(8)));

__device__ __forceinline__ ushort f2bf(float f) {
    unsigned u = __float_as_uint(f);
    return (ushort)((u + 0x7FFFu + ((u >> 16) & 1u)) >> 16);   // RNE
}
__device__ __forceinline__ float bf2f(ushort h) {
    return __uint_as_float(((unsigned)h) << 16);
}

// ---------------- zero int buffer ----------------
__global__ void kzero(int* __restrict__ p, int n) {
    int i = blockIdx.x * blockDim.x + threadIdx.x;
    if (i < n) p[i] = 0;
}

// ---------------- prep: transpose + split fp32 -> bf16 hi/lo (for W_att) ----------------
__global__ void ksplitT(const float* __restrict__ src, ushort* __restrict__ hi,
                        ushort* __restrict__ lo, int R, int C) {
    __shared__ float tile[32][33];
    const int tc = blockIdx.x * 32, tr = blockIdx.y * 32;
    const int lx = threadIdx.x, ly = threadIdx.y;      // 32 x 8
    for (int i = 0; i < 32; i += 8) {
        int r = tr + ly + i, c = tc + lx;
        tile[ly + i][lx] = (r < R && c < C) ? src[(size_t)r * C + c] : 0.f;
    }
    __syncthreads();
    for (int i = 0; i < 32; i += 8) {
        int c = tc + ly + i, r = tr + lx;
        if (c < C && r < R) {
            float f = tile[lx][ly + i];
            ushort h = f2bf(f);
            hi[(size_t)c * R + r] = h;
            lo[(size_t)c * R + r] = f2bf(f - bf2f(h));
        }
    }
}

// ---------------- prep: attention weight fold ----------------
__global__ void kattw(const float* __restrict__ W, const float* __restrict__ asrc,
                      const float* __restrict__ adst, ushort* __restrict__ hi,
                      ushort* __restrict__ lo) {
    const int k = threadIdx.x;   // 128 threads
    for (int h = 0; h < HH; ++h) {
        float s1 = 0.f, s2 = 0.f;
        #pragma unroll
        for (int dh = 0; dh < 16; ++dh) {
            float w = W[k * DD + h * 16 + dh];
            s1 = fmaf(w, asrc[h * 16 + dh], s1);
            s2 = fmaf(w, adst[h * 16 + dh], s2);
        }
        ushort h1 = f2bf(s1);
        hi[(128 + h) * DD + k] = h1;
        lo[(128 + h) * DD + k] = f2bf(s1 - bf2f(h1));
        ushort h2 = f2bf(s2);
        hi[(136 + h) * DD + k] = h2;
        lo[(136 + h) * DD + k] = f2bf(s2 - bf2f(h2));
    }
}

// ---------------- prep: W1/W2 -> MFMA-fragment-order bf16 hi/lo planes ----------------
// W1F frag index f = ((ch*2 + tc)*4 + s)*64 + lane; frag = W1[k0..k0+8)[ff] with
// ff = ch*32 + tc*16 + (lane&15), k0 = s*32 + (lane>>4)*8. Chunk ch = 4096 contiguous ushorts.
__global__ void kfrag1(const float* __restrict__ W1, ushort* __restrict__ hi,
                       ushort* __restrict__ lo) {
    const int f = blockIdx.x * 256 + threadIdx.x;    // 8192 frags
    const int l = f & 63, s = (f >> 6) & 3, tc = (f >> 8) & 1, ch = f >> 9;
    const int ff = ch * 32 + tc * 16 + (l & 15);
    const int k0 = s * 32 + (l >> 4) * 8;
    #pragma unroll
    for (int j = 0; j < 8; ++j) {
        float w = W1[(size_t)(k0 + j) * DFF + ff];
        ushort h = f2bf(w);
        hi[f * 8 + j] = h;
        lo[f * 8 + j] = f2bf(w - bf2f(h));
    }
}
// W2F frag index f = (ch*8 + oc)*64 + lane; frag = W2[k0..k0+8)[out] with
// out = oc*16 + (lane&15), k0 = ch*32 + (lane>>4)*8.
__global__ void kfrag2(const float* __restrict__ W2, ushort* __restrict__ hi,
                       ushort* __restrict__ lo) {
    const int f = blockIdx.x * 256 + threadIdx.x;    // 8192 frags
    const int l = f & 63, oc = (f >> 6) & 7, ch = f >> 9;
    const int out = oc * 16 + (l & 15);
    const int k0 = ch * 32 + (l >> 4) * 8;
    #pragma unroll
    for (int j = 0; j < 8; ++j) {
        float w = W2[(size_t)(k0 + j) * DD + out];
        ushort h = f2bf(w);
        hi[f * 8 + j] = h;
        lo[f * 8 + j] = f2bf(w - bf2f(h));
    }
}

// ---------------- K1: LN1 + [x | a_s | a_d] = ln1 @ [W_att | Was | Wad] via MFMA ----------------
__global__ __launch_bounds__(256) void k1_mfma(
    const float* __restrict__ nf, const float* __restrict__ g, const float* __restrict__ b,
    const ushort* __restrict__ WAhi, const ushort* __restrict__ WAlo,
    float* __restrict__ x, float* __restrict__ a_s, float* __restrict__ a_d, int n) {
    const int tid = threadIdx.x;
    const int w = tid >> 6, l = tid & 63;
    const int l15 = l & 15, l4 = l >> 4;
    const int nbase = blockIdx.x * TM;
    int arow = nbase + w * 16 + l15;
    if (arow >= n) arow = n - 1;

    float v[4][8];
    const float* ap = nf + (size_t)arow * DD + l4 * 8;
    #pragma unroll
    for (int s = 0; s < 4; ++s) {
        *(float4*)&v[s][0] = *(const float4*)(ap + s * 32);
        *(float4*)&v[s][4] = *(const float4*)(ap + s * 32 + 4);
    }
    float sum = 0.f;
    #pragma unroll
    for (int s = 0; s < 4; ++s)
        #pragma unroll
        for (int j = 0; j < 8; ++j) sum += v[s][j];
    sum += __shfl_xor(sum, 16);
    sum += __shfl_xor(sum, 32);
    const float mean = sum * (1.f / DD);
    float qs = 0.f;
    #pragma unroll
    for (int s = 0; s < 4; ++s)
        #pragma unroll
        for (int j = 0; j < 8; ++j) { float d = v[s][j] - mean; qs += d * d; }
    qs += __shfl_xor(qs, 16);
    qs += __shfl_xor(qs, 32);
    const float iv = 1.f / (sqrtf(qs * (1.f / (DD - 1))) + EPS);

    bf16x8 Ahi[4], Alo[4];
    #pragma unroll
    for (int s = 0; s < 4; ++s) {
        const int k0 = s * 32 + l4 * 8;
        float gv[8], bv[8];
        *(float4*)&gv[0] = *(const float4*)(g + k0);
        *(float4*)&gv[4] = *(const float4*)(g + k0 + 4);
        *(float4*)&bv[0] = *(const float4*)(b + k0);
        *(float4*)&bv[4] = *(const float4*)(b + k0 + 4);
        bf16x8 hv, lv;
        #pragma unroll
        for (int j = 0; j < 8; ++j) {
            float f = fmaf(gv[j], (v[s][j] - mean) * iv, bv[j]);
            ushort hb = f2bf(f);
            hv[j] = (short)hb;
            lv[j] = (short)f2bf(f - bf2f(hb));
        }
        Ahi[s] = hv; Alo[s] = lv;
    }

    #pragma unroll
    for (int oc = 0; oc < 9; ++oc) {
        f32x4 acc = (f32x4){0.f, 0.f, 0.f, 0.f};
        const ushort* bp = WAhi + (size_t)(oc * 16 + l15) * DD + l4 * 8;
        const ushort* lp = WAlo + (size_t)(oc * 16 + l15) * DD + l4 * 8;
        #pragma unroll
        for (int s = 0; s < 4; ++s) {
            bf16x8 bh = *(const bf16x8*)(bp + s * 32);
            bf16x8 bl = *(const bf16x8*)(lp + s * 32);
            acc = __builtin_amdgcn_mfma_f32_16x16x32_bf16(Ahi[s], bh, acc, 0, 0, 0);
            acc = __builtin_amdgcn_mfma_f32_16x16x32_bf16(Alo[s], bh, acc, 0, 0, 0);
            acc = __builtin_amdgcn_mfma_f32_16x16x32_bf16(Ahi[s], bl, acc, 0, 0, 0);
        }
        #pragma unroll
        for (int i = 0; i < 4; ++i) {
            const int node = nbase + w * 16 + l4 * 4 + i;
            if (node < n) {
                if (oc < 8) x[(size_t)node * DD + oc * 16 + l15] = acc[i];
                else if (l15 < 8) a_s[node * HH + l15] = acc[i];
                else a_d[node * HH + (l15 - 8)] = acc[i];
            }
        }
    }
}

// ---------------- K2: in-degree count ----------------
__global__ void k2_deg(const int* __restrict__ ei, int* __restrict__ deg, int E) {
    int e = blockIdx.x * blockDim.x + threadIdx.x;
    if (e < E) atomicAdd(&deg[ei[E + e]], 1);
}

// ---------------- K3a/b/c: hierarchical exclusive scan ----------------
__global__ __launch_bounds__(1024) void k3a(const int* __restrict__ deg, int* __restrict__ incl,
                                            int* __restrict__ bsum, int n) {
    __shared__ int wsum[16];
    const int b = blockIdx.x, t = threadIdx.x;
    const int i0 = b * 4096 + t * 4;
    int4 v = make_int4(0, 0, 0, 0);
    if (i0 + 3 < n) v = *(const int4*)&deg[i0];
    else {
        int* vp = (int*)&v;
        for (int q = 0; q < 4; ++q) vp[q] = (i0 + q < n) ? deg[i0 + q] : 0;
    }
    const int s1 = v.x, s2 = s1 + v.y, s3 = s2 + v.z, s4 = s3 + v.w;
    const int lane = t & 63, wv = t >> 6;
    int xx = s4;
    #pragma unroll
    for (int off = 1; off < 64; off <<= 1) {
        int y = __shfl_up(xx, off);
        if (lane >= off) xx += y;
    }
    if (lane == 63) wsum[wv] = xx;
    __syncthreads();
    if (wv == 0) {
        int y = (lane < 16) ? wsum[lane] : 0;
        #pragma unroll
        for (int off = 1; off < 16; off <<= 1) {
            int z = __shfl_up(y, off);
            if (lane >= off) y += z;
        }
        if (lane < 16) wsum[lane] = y;
    }
    __syncthreads();
    const int wbase = (wv == 0) ? 0 : wsum[wv - 1];
    const int excl = xx - s4 + wbase;
    if (i0 < n) {
        int4 o = make_int4(excl + s1, excl + s2, excl + s3, excl + s4);
        if (i0 + 3 < n) *(int4*)&incl[i0] = o;
        else {
            int* op = (int*)&o;
            for (int q = 0; q < 4; ++q) if (i0 + q < n) incl[i0 + q] = op[q];
        }
    }
    if (t == 1023) bsum[b] = wbase + xx;
}

__global__ void k3b(int* __restrict__ bsum, int nb) {
    int t = threadIdx.x;
    int v = (t < nb) ? bsum[t] : 0;
    #pragma unroll
    for (int off = 1; off < 64; off <<= 1) {
        int y = __shfl_up(v, off);
        if (t >= off) v += y;
    }
    if (t < nb) bsum[t] = v;   // inclusive
}

__global__ void k3c(const int* __restrict__ incl, const int* __restrict__ bsum,
                    const int* __restrict__ deg, int* __restrict__ row_ptr,
                    int* __restrict__ cursor, int n) {
    int i = blockIdx.x * blockDim.x + threadIdx.x;
    if (i < n) {
        int b = i >> 12;
        int base = b ? bsum[b - 1] : 0;
        int inc = incl[i] + base;
        row_ptr[i + 1] = inc;
        cursor[i] = inc - deg[i];
        if (i == 0) row_ptr[0] = 0;
    }
}

// ---------------- K4: scatter src ids into CSR ----------------
__global__ void k4_scatter(const int* __restrict__ ei, int* __restrict__ cursor,
                           int* __restrict__ col_src, int E) {
    int e = blockIdx.x * blockDim.x + threadIdx.x;
    if (e < E) {
        int dst = ei[E + e];
        int pos = atomicAdd(&cursor[dst], 1);
        col_src[pos] = ei[e];
    }
}

// ---------------- K5: per-dst online-softmax gather + residual + LN2 ----------------
__global__ __launch_bounds__(256) void k5_gather(
    const float* __restrict__ x, const float* __restrict__ a_s, const float* __restrict__ a_d,
    const int* __restrict__ row_ptr, const int* __restrict__ col_src,
    const float* __restrict__ nf, const float* __restrict__ bias_att,
    const float* __restrict__ ln2g, const float* __restrict__ ln2b,
    float* __restrict__ nf1, float* __restrict__ h2, int n) {
    const int w = (blockIdx.x * blockDim.x + threadIdx.x) >> 6;
    if (w >= n) return;
    const int lane = threadIdx.x & 63;
    const int h = lane >> 3;
    const int c0 = lane * 2;
    const float ad = a_d[w * HH + h];
    float e = a_s[w * HH + h] + ad;
    e = e > 0.f ? e : SLOPE * e;
    float m = e, denom = 1.f;
    float2 xv = *(const float2*)&x[(size_t)w * DD + c0];
    float acc0 = xv.x, acc1 = xv.y;
    const int beg = row_ptr[w], end = row_ptr[w + 1];
    int j = beg;
    const int j4end = beg + ((end - beg) & ~3);

#define BATCH_MATH(F0, F1, F2, F3, X0, X1, X2, X3) {                                   \
        float f0 = (F0) + ad, f1 = (F1) + ad, f2 = (F2) + ad, f3 = (F3) + ad;          \
        f0 = f0 > 0.f ? f0 : SLOPE * f0;  f1 = f1 > 0.f ? f1 : SLOPE * f1;             \
        f2 = f2 > 0.f ? f2 : SLOPE * f2;  f3 = f3 > 0.f ? f3 : SLOPE * f3;             \
        const float mb = fmaxf(fmaxf(f0, f1), fmaxf(f2, f3));                          \
        const float nm = fmaxf(m, mb);                                                 \
        const float sc = __expf(m - nm);                                               \
        const float p0 = __expf(f0 - nm), p1 = __expf(f1 - nm);                        \
        const float p2 = __expf(f2 - nm), p3 = __expf(f3 - nm);                        \
        denom = denom * sc + ((p0 + p1) + (p2 + p3));                                  \
        acc0 = acc0 * sc + (fmaf(X0.x, p0, X1.x * p1) + fmaf(X2.x, p2, X3.x * p3));    \
        acc1 = acc1 * sc + (fmaf(X0.y, p0, X1.y * p1) + fmaf(X2.y, p2, X3.y * p3));    \
        m = nm; }

    if (j < j4end) {
        int s0 = col_src[j], s1 = col_src[j + 1], s2 = col_src[j + 2], s3 = col_src[j + 3];
        float e0 = a_s[s0 * HH + h], e1 = a_s[s1 * HH + h];
        float e2 = a_s[s2 * HH + h], e3 = a_s[s3 * HH + h];
        float2 x0 = *(const float2*)&x[(size_t)s0 * DD + c0];
        float2 x1 = *(const float2*)&x[(size_t)s1 * DD + c0];
        float2 x2 = *(const float2*)&x[(size_t)s2 * DD + c0];
        float2 x3 = *(const float2*)&x[(size_t)s3 * DD + c0];
        for (j += 4;; j += 4) {
            const bool more = j < j4end;
            float ne0, ne1, ne2, ne3;
            float2 nx0, nx1, nx2, nx3;
            if (more) {
                const int t0 = col_src[j], t1 = col_src[j + 1];
                const int t2 = col_src[j + 2], t3 = col_src[j + 3];
                ne0 = a_s[t0 * HH + h]; ne1 = a_s[t1 * HH + h];
                ne2 = a_s[t2 * HH + h]; ne3 = a_s[t3 * HH + h];
                nx0 = *(const float2*)&x[(size_t)t0 * DD + c0];
                nx1 = *(const float2*)&x[(size_t)t1 * DD + c0];
                nx2 = *(const float2*)&x[(size_t)t2 * DD + c0];
                nx3 = *(const float2*)&x[(size_t)t3 * DD + c0];
            }
            BATCH_MATH(e0, e1, e2, e3, x0, x1, x2, x3)
            if (!more) break;
            e0 = ne0; e1 = ne1; e2 = ne2; e3 = ne3;
            x0 = nx0; x1 = nx1; x2 = nx2; x3 = nx3;
        }
    }
    for (; j < end; ++j) {
        const int s0 = col_src[j];
        float ev = a_s[s0 * HH + h] + ad;
        ev = ev > 0.f ? ev : SLOPE * ev;
        const float2 x0 = *(const float2*)&x[(size_t)s0 * DD + c0];
        const float nm = fmaxf(m, ev);
        const float sc = __expf(m - nm);
        const float pp = __expf(ev - nm);
        denom = denom * sc + pp;
        acc0 = acc0 * sc + x0.x * pp;
        acc1 = acc1 * sc + x0.y * pp;
        m = nm;
    }
#undef BATCH_MATH
    const float inv = 1.f / (denom + 1e-16f);
    float o0 = acc0 * inv + bias_att[c0]     + nf[(size_t)w * DD + c0];
    float o1 = acc1 * inv + bias_att[c0 + 1] + nf[(size_t)w * DD + c0 + 1];
    *(float2*)&nf1[(size_t)w * DD + c0] = make_float2(o0, o1);
    float s = o0 + o1;
    #pragma unroll
    for (int o = 32; o >= 1; o >>= 1) s += __shfl_xor(s, o);
    const float mean = s * (1.f / DD);
    const float d0 = o0 - mean, d1 = o1 - mean;
    float q = d0 * d0 + d1 * d1;
    #pragma unroll
    for (int o = 32; o >= 1; o >>= 1) q += __shfl_xor(q, o);
    const float var = q * (1.f / (DD - 1));
    const float iv = 1.f / (sqrtf(var) + EPS);
    float z0 = ln2g[c0] * d0 * iv + ln2b[c0];
    float z1 = ln2g[c0 + 1] * d1 * iv + ln2b[c0 + 1];
    *(float2*)&h2[(size_t)w * DD + c0] = make_float2(z0, z1);
}

// ---------------- K6: split-bf16 MFMA FFN, 2-phase dbuf pipeline ----------------
// Frag-order weights: LDS reads are base+lane*16 (conflict-free). 16 chunks of 32 ff;
// per chunk: prefetch chunk+1 to regs -> compute from buf[cur] -> barrier ->
// ds_write regs to buf[cur^1] -> barrier. Global latency hides under chunk compute.
__global__ __launch_bounds__(256, 2) void k6_mfma(
    const float* __restrict__ h2, const float* __restrict__ nf1,
    const ushort* __restrict__ W1Fhi, const ushort* __restrict__ W1Flo,
    const ushort* __restrict__ W2Fhi, const ushort* __restrict__ W2Flo,
    const float* __restrict__ b1, const float* __restrict__ b2,
    float* __restrict__ out, int n) {
    __shared__ ushort buf[2][16384];   // 64KB: [W1hi 8KB | W1lo 8KB | W2hi 8KB | W2lo 8KB] x2
    __shared__ float hhs[2048];        // 8KB: 4 waves x [16 nodes][32 ff] swizzled
    const int tid = threadIdx.x;
    const int w = tid >> 6, l = tid & 63;
    const int l15 = l & 15, l4 = l >> 4;
    const int nbase = blockIdx.x * TM;
    char* hw = (char*)hhs + w * 2048;

    // ---- A-frags: this wave's 16 node rows of h2, split into hi/lo bf16
    int arow = nbase + w * 16 + l15;
    if (arow >= n) arow = n - 1;                    // clamp; tail writes guarded
    const float* ap = h2 + (size_t)arow * DD + l4 * 8;
    bf16x8 Ahi[4], Alo[4];
    #pragma unroll
    for (int s = 0; s < 4; ++s) {
        float v[8];
        *(float4*)&v[0] = *(const float4*)(ap + s * 32);
        *(float4*)&v[4] = *(const float4*)(ap + s * 32 + 4);
        bf16x8 hv, lv;
        #pragma unroll
        for (int jj = 0; jj < 8; ++jj) {
            ushort hb = f2bf(v[jj]);
            hv[jj] = (short)hb;
            lv[jj] = (short)f2bf(v[jj] - bf2f(hb));
        }
        Ahi[s] = hv; Alo[s] = lv;
    }

    f32x4 acc_o[8];
    #pragma unroll
    for (int oc = 0; oc < 8; ++oc) acc_o[oc] = (f32x4){0.f, 0.f, 0.f, 0.f};

    // ---- prologue: stage chunk 0 into buf[0]
    #pragma unroll
    for (int p = 0; p < 2; ++p) {
        const int o8 = (p * 256 + tid) * 8;
        const int o16 = (p * 256 + tid) * 16;
        *(bf16x8*)((char*)buf + 0     + o16) = *(const bf16x8*)(W1Fhi + o8);
        *(bf16x8*)((char*)buf + 8192  + o16) = *(const bf16x8*)(W1Flo + o8);
        *(bf16x8*)((char*)buf + 16384 + o16) = *(const bf16x8*)(W2Fhi + o8);
        *(bf16x8*)((char*)buf + 24576 + o16) = *(const bf16x8*)(W2Flo + o8);
    }
    __syncthreads();

    int cur = 0;
    #pragma unroll 1
    for (int ch = 0; ch < 16; ++ch) {
        // ---- issue next-chunk global loads (consumed after the compute phase)
        bf16x8 st[8];
        if (ch < 15) {
            const int u = (ch + 1) * 4096;
            #pragma unroll
            for (int p = 0; p < 2; ++p) {
                const int o8 = u + (p * 256 + tid) * 8;
                st[0 + p] = *(const bf16x8*)(W1Fhi + o8);
                st[2 + p] = *(const bf16x8*)(W1Flo + o8);
                st[4 + p] = *(const bf16x8*)(W2Fhi + o8);
                st[6 + p] = *(const bf16x8*)(W2Flo + o8);
            }
        }
        const char* cb = (const char*)buf + cur;
        // ---- stage A: hh[16 nodes][32 ff] = relu(h2 @ W1_chunk + b1)
        #pragma unroll
        for (int tc = 0; tc < 2; ++tc) {
            f32x4 a = (f32x4){0.f, 0.f, 0.f, 0.f};
            #pragma unroll
            for (int s = 0; s < 4; ++s) {
                const int fo = ((tc * 4 + s) * 64 + l) * 16;
                bf16x8 bh = *(const bf16x8*)(cb + fo);
                bf16x8 bl = *(const bf16x8*)(cb + 8192 + fo);
                a = __builtin_amdgcn_mfma_f32_16x16x32_bf16(Ahi[s], bh, a, 0, 0, 0);
                a = __builtin_amdgcn_mfma_f32_16x16x32_bf16(Alo[s], bh, a, 0, 0, 0);
                a = __builtin_amdgcn_mfma_f32_16x16x32_bf16(Ahi[s], bl, a, 0, 0, 0);
            }
            const float bias = b1[ch * 32 + tc * 16 + l15];
            #pragma unroll
            for (int i = 0; i < 4; ++i) {
                const int row = l4 * 4 + i;
                const int byte = (row * 128 + (tc * 16 + l15) * 4) ^ ((row & 7) << 4);
                *(float*)(hw + byte) = fmaxf(a[i] + bias, 0.f);
            }
        }
        // ---- transpose read-back (wave-private; lgkmcnt ordering, no barrier)
        bf16x8 Phi, Plo;
        {
            const int base = (l15 * 128 + l4 * 32);
            const int msk = (l15 & 7) << 4;
            float v[8];
            *(float4*)&v[0] = *(const float4*)(hw + (base ^ msk));
            *(float4*)&v[4] = *(const float4*)(hw + ((base + 16) ^ msk));
            #pragma unroll
            for (int jj = 0; jj < 8; ++jj) {
                ushort hb = f2bf(v[jj]);
                Phi[jj] = (short)hb;
                Plo[jj] = (short)f2bf(v[jj] - bf2f(hb));
            }
        }
        // ---- stage B: acc_o += hh @ W2_chunk
        #pragma unroll
        for (int oc = 0; oc < 8; ++oc) {
            const int fo = (oc * 64 + l) * 16;
            bf16x8 bh = *(const bf16x8*)(cb + 16384 + fo);
            bf16x8 bl = *(const bf16x8*)(cb + 24576 + fo);
            acc_o[oc] = __builtin_amdgcn_mfma_f32_16x16x32_bf16(Phi, bh, acc_o[oc], 0, 0, 0);
            acc_o[oc] = __builtin_amdgcn_mfma_f32_16x16x32_bf16(Plo, bh, acc_o[oc], 0, 0, 0);
            acc_o[oc] = __builtin_amdgcn_mfma_f32_16x16x32_bf16(Phi, bl, acc_o[oc], 0, 0, 0);
        }
        __syncthreads();                   // all waves done reading buf[cur]
        if (ch < 15) {
            char* db = (char*)buf + (cur ^ 32768);
            #pragma unroll
            for (int p = 0; p < 2; ++p) {
                const int o16 = (p * 256 + tid) * 16;
                *(bf16x8*)(db + 0     + o16) = st[0 + p];
                *(bf16x8*)(db + 8192  + o16) = st[2 + p];
                *(bf16x8*)(db + 16384 + o16) = st[4 + p];
                *(bf16x8*)(db + 24576 + o16) = st[6 + p];
            }
            __syncthreads();               // next buffer visible
            cur ^= 32768;
        }
    }
    // ---- epilogue: + b2 + residual
    #pragma unroll
    for (int oc = 0; oc < 8; ++oc) {
        const int col = oc * 16 + l15;
        const float b2v = b2[col];
        #pragma unroll
        for (int i = 0; i < 4; ++i) {
            const int node = nbase + w * 16 + l4 * 4 + i;
            if (node < n)
                out[(size_t)node * DD + col] = acc_o[oc][i] + b2v + nf1[(size_t)node * DD + col];
        }
    }
}

extern "C" void kernel_launch(void* const* d_in, const int* in_sizes, int n_in,
                              void* d_out, int out_size, void* d_ws, size_t ws_size,
                              hipStream_t stream) {
    const float* nf       = (const float*)d_in[0];
    const int*   ei       = (const int*)d_in[1];
    const float* ln1_g    = (const float*)d_in[2];
    const float* ln1_b    = (const float*)d_in[3];
    const float* W_att    = (const float*)d_in[4];
    const float* att_src  = (const float*)d_in[5];
    const float* att_dst  = (const float*)d_in[6];
    const float* bias_att = (const float*)d_in[7];
    const float* ln2_g    = (const float*)d_in[8];
    const float* ln2_b    = (const float*)d_in[9];
    const float* W1       = (const float*)d_in[10];
    const float* b1       = (const float*)d_in[11];
    const float* W2       = (const float*)d_in[12];
    const float* b2       = (const float*)d_in[13];
    const int n = in_sizes[0] / DD;
    const int E = in_sizes[1] / 2;

    char* ws = (char*)d_ws;
    size_t off = 0;
    auto alloc = [&](size_t bytes) {
        off = (off + 255) & ~(size_t)255;
        char* p = ws + off;
        off += bytes;
        return p;
    };
    float*  x       = (float*)alloc((size_t)n * DD * 4);
    float*  a_s     = (float*)alloc((size_t)n * HH * 4);
    float*  a_d     = (float*)alloc((size_t)n * HH * 4);
    float*  nf1     = (float*)alloc((size_t)n * DD * 4);
    float*  h2      = (float*)alloc((size_t)n * DD * 4);
    int*    row_ptr = (int*)alloc((size_t)(n + 1) * 4);
    int*    cursor  = (int*)alloc((size_t)n * 4);
    int*    deg     = (int*)alloc((size_t)n * 4);
    int*    incl    = (int*)alloc((size_t)n * 4);
    int*    bsum    = (int*)alloc(64 * 4);
    int*    col_src = (int*)alloc((size_t)E * 4);
    ushort* WAhi    = (ushort*)alloc((size_t)144 * DD * 2);   // [W_att^T | Was | Wad]
    ushort* WAlo    = (ushort*)alloc((size_t)144 * DD * 2);
    ushort* W1Fhi   = (ushort*)alloc((size_t)DFF * DD * 2);   // frag-order planes
    ushort* W1Flo   = (ushort*)alloc((size_t)DFF * DD * 2);
    ushort* W2Fhi   = (ushort*)alloc((size_t)DD * DFF * 2);
    ushort* W2Flo   = (ushort*)alloc((size_t)DD * DFF * 2);
    (void)ws_size; (void)n_in; (void)out_size;

    const int nb3 = (n + 4095) / 4096;

    ksplitT<<<dim3(DD / 32, DD / 32), dim3(32, 8), 0, stream>>>(W_att, WAhi, WAlo, DD, DD);
    kattw<<<1, 128, 0, stream>>>(W_att, att_src, att_dst, WAhi, WAlo);
    kfrag1<<<32, 256, 0, stream>>>(W1, W1Fhi, W1Flo);
    kfrag2<<<32, 256, 0, stream>>>(W2, W2Fhi, W2Flo);
    kzero<<<(n + 255) / 256, 256, 0, stream>>>(deg, n);
    k1_mfma<<<(n + TM - 1) / TM, 256, 0, stream>>>(nf, ln1_g, ln1_b, WAhi, WAlo, x, a_s, a_d, n);
    k2_deg<<<(E + 255) / 256, 256, 0, stream>>>(ei, deg, E);
    k3a<<<nb3, 1024, 0, stream>>>(deg, incl, bsum, n);
    k3b<<<1, 64, 0, stream>>>(bsum, nb3);
    k3c<<<(n + 255) / 256, 256, 0, stream>>>(incl, bsum, deg, row_ptr, cursor, n);
    k4_scatter<<<(E + 255) / 256, 256, 0, stream>>>(ei, cursor, col_src, E);
    k5_gather<<<(n + 3) / 4, 256, 0, stream>>>(x, a_s, a_d, row_ptr, col_src, nf, bias_att,
                                               ln2_g, ln2_b, nf1, h2, n);
    k6_mfma<<<(n + TM - 1) / TM, 256, 0, stream>>>(h2, nf1, W1Fhi, W1Flo, W2Fhi, W2Flo,
                                                   b1, b2, (float*)d_out, n);
}

// Round 7
// 354.292 us; speedup vs baseline: 1.6200x; 1.1364x over previous
//
#include <hip/hip_runtime.h>

#define DD 128
#define HH 8
#define DFF 512
#define EPS 1e-6f
#define SLOPE 0.2f
#define TM 64
#define TM6 128

typedef float f32x4 __attribute__((ext_vector_type(4)));
typedef short bf16x8 __attribute__((ext_vector_type(8)));

__device__ __forceinline__ ushort f2bf(float f) {
    unsigned u = __float_as_uint(f);
    return (ushort)((u + 0x7FFFu + ((u >> 16) & 1u)) >> 16);   // RNE
}
__device__ __forceinline__ float bf2f(ushort h) {
    return __uint_as_float(((unsigned)h) << 16);
}

// ================= P0: fused prep (kzero | ksplitT(W_att) | kattw | kfrag1 | kfrag2) ==========
__device__ void d_splitT(int bp, int tid, const float* __restrict__ src,
                         ushort* __restrict__ hi, ushort* __restrict__ lo, int R, int C) {
    __shared__ float tile[32][33];
    const int tc = (bp & 3) * 32, tr = (bp >> 2) * 32;
    const int lx = tid & 31, ly = tid >> 5;            // 32 x 8
    for (int i = 0; i < 32; i += 8) {
        int r = tr + ly + i, c = tc + lx;
        tile[ly + i][lx] = (r < R && c < C) ? src[(size_t)r * C + c] : 0.f;
    }
    __syncthreads();
    for (int i = 0; i < 32; i += 8) {
        int c = tc + ly + i, r = tr + lx;
        if (c < C && r < R) {
            float f = tile[lx][ly + i];
            ushort h = f2bf(f);
            hi[(size_t)c * R + r] = h;
            lo[(size_t)c * R + r] = f2bf(f - bf2f(h));
        }
    }
}

__device__ void d_attw(int tid, const float* __restrict__ W, const float* __restrict__ asrc,
                       const float* __restrict__ adst, ushort* __restrict__ hi,
                       ushort* __restrict__ lo) {
    if (tid >= DD) return;
    const int k = tid;
    for (int h = 0; h < HH; ++h) {
        float s1 = 0.f, s2 = 0.f;
        #pragma unroll
        for (int dh = 0; dh < 16; ++dh) {
            float w = W[k * DD + h * 16 + dh];
            s1 = fmaf(w, asrc[h * 16 + dh], s1);
            s2 = fmaf(w, adst[h * 16 + dh], s2);
        }
        ushort h1 = f2bf(s1);
        hi[(128 + h) * DD + k] = h1;
        lo[(128 + h) * DD + k] = f2bf(s1 - bf2f(h1));
        ushort h2 = f2bf(s2);
        hi[(136 + h) * DD + k] = h2;
        lo[(136 + h) * DD + k] = f2bf(s2 - bf2f(h2));
    }
}

__device__ void d_frag1(int bp, int tid, const float* __restrict__ W1,
                        ushort* __restrict__ hi, ushort* __restrict__ lo) {
    const int f = bp * 256 + tid;                      // 8192 frags
    const int l = f & 63, s = (f >> 6) & 3, tc = (f >> 8) & 1, ch = f >> 9;
    const int ff = ch * 32 + tc * 16 + (l & 15);
    const int k0 = s * 32 + (l >> 4) * 8;
    #pragma unroll
    for (int j = 0; j < 8; ++j) {
        float w = W1[(size_t)(k0 + j) * DFF + ff];
        ushort h = f2bf(w);
        hi[f * 8 + j] = h;
        lo[f * 8 + j] = f2bf(w - bf2f(h));
    }
}

__device__ void d_frag2(int bp, int tid, const float* __restrict__ W2,
                        ushort* __restrict__ hi, ushort* __restrict__ lo) {
    const int f = bp * 256 + tid;                      // 8192 frags
    const int l = f & 63, oc = (f >> 6) & 7, ch = f >> 9;
    const int out = oc * 16 + (l & 15);
    const int k0 = ch * 32 + (l >> 4) * 8;
    #pragma unroll
    for (int j = 0; j < 8; ++j) {
        float w = W2[(size_t)(k0 + j) * DD + out];
        ushort h = f2bf(w);
        hi[f * 8 + j] = h;
        lo[f * 8 + j] = f2bf(w - bf2f(h));
    }
}

__global__ __launch_bounds__(256) void p0_prep(
    const float* __restrict__ W_att, const float* __restrict__ asrc,
    const float* __restrict__ adst, const float* __restrict__ W1, const float* __restrict__ W2,
    ushort* __restrict__ WAhi, ushort* __restrict__ WAlo,
    ushort* __restrict__ W1Fhi, ushort* __restrict__ W1Flo,
    ushort* __restrict__ W2Fhi, ushort* __restrict__ W2Flo,
    int* __restrict__ deg, int n) {
    const int bp = blockIdx.x, tid = threadIdx.x;
    if (bp < 16)            d_splitT(bp, tid, W_att, WAhi, WAlo, DD, DD);
    else if (bp == 16)      d_attw(tid, W_att, asrc, adst, WAhi, WAlo);
    else if (bp < 49)       d_frag1(bp - 17, tid, W1, W1Fhi, W1Flo);
    else if (bp < 81)       d_frag2(bp - 49, tid, W2, W2Fhi, W2Flo);
    else {
        int i = (bp - 81) * 256 + tid;
        if (i < n) deg[i] = 0;
    }
}

// ================= P1: fused k1_mfma | k2_deg (independent work, concurrent) =================
__device__ void d_k1(int bid, int tid,
                     const float* __restrict__ nf, const float* __restrict__ g,
                     const float* __restrict__ b, const ushort* __restrict__ WAhi,
                     const ushort* __restrict__ WAlo, float* __restrict__ x,
                     float* __restrict__ a_s, float* __restrict__ a_d, int n) {
    const int w = tid >> 6, l = tid & 63;
    const int l15 = l & 15, l4 = l >> 4;
    const int nbase = bid * TM;
    int arow = nbase + w * 16 + l15;
    if (arow >= n) arow = n - 1;

    float v[4][8];
    const float* ap = nf + (size_t)arow * DD + l4 * 8;
    #pragma unroll
    for (int s = 0; s < 4; ++s) {
        *(float4*)&v[s][0] = *(const float4*)(ap + s * 32);
        *(float4*)&v[s][4] = *(const float4*)(ap + s * 32 + 4);
    }
    float sum = 0.f;
    #pragma unroll
    for (int s = 0; s < 4; ++s)
        #pragma unroll
        for (int j = 0; j < 8; ++j) sum += v[s][j];
    sum += __shfl_xor(sum, 16);
    sum += __shfl_xor(sum, 32);
    const float mean = sum * (1.f / DD);
    float qs = 0.f;
    #pragma unroll
    for (int s = 0; s < 4; ++s)
        #pragma unroll
        for (int j = 0; j < 8; ++j) { float d = v[s][j] - mean; qs += d * d; }
    qs += __shfl_xor(qs, 16);
    qs += __shfl_xor(qs, 32);
    const float iv = 1.f / (sqrtf(qs * (1.f / (DD - 1))) + EPS);

    bf16x8 Ahi[4], Alo[4];
    #pragma unroll
    for (int s = 0; s < 4; ++s) {
        const int k0 = s * 32 + l4 * 8;
        float gv[8], bv[8];
        *(float4*)&gv[0] = *(const float4*)(g + k0);
        *(float4*)&gv[4] = *(const float4*)(g + k0 + 4);
        *(float4*)&bv[0] = *(const float4*)(b + k0);
        *(float4*)&bv[4] = *(const float4*)(b + k0 + 4);
        bf16x8 hv, lv;
        #pragma unroll
        for (int j = 0; j < 8; ++j) {
            float f = fmaf(gv[j], (v[s][j] - mean) * iv, bv[j]);
            ushort hb = f2bf(f);
            hv[j] = (short)hb;
            lv[j] = (short)f2bf(f - bf2f(hb));
        }
        Ahi[s] = hv; Alo[s] = lv;
    }

    #pragma unroll
    for (int oc = 0; oc < 9; ++oc) {
        f32x4 acc = (f32x4){0.f, 0.f, 0.f, 0.f};
        const ushort* bp = WAhi + (size_t)(oc * 16 + l15) * DD + l4 * 8;
        const ushort* lp = WAlo + (size_t)(oc * 16 + l15) * DD + l4 * 8;
        #pragma unroll
        for (int s = 0; s < 4; ++s) {
            bf16x8 bh = *(const bf16x8*)(bp + s * 32);
            bf16x8 bl = *(const bf16x8*)(lp + s * 32);
            acc = __builtin_amdgcn_mfma_f32_16x16x32_bf16(Ahi[s], bh, acc, 0, 0, 0);
            acc = __builtin_amdgcn_mfma_f32_16x16x32_bf16(Alo[s], bh, acc, 0, 0, 0);
            acc = __builtin_amdgcn_mfma_f32_16x16x32_bf16(Ahi[s], bl, acc, 0, 0, 0);
        }
        #pragma unroll
        for (int i = 0; i < 4; ++i) {
            const int node = nbase + w * 16 + l4 * 4 + i;
            if (node < n) {
                if (oc < 8) x[(size_t)node * DD + oc * 16 + l15] = acc[i];
                else if (l15 < 8) a_s[node * HH + l15] = acc[i];
                else a_d[node * HH + (l15 - 8)] = acc[i];
            }
        }
    }
}

__global__ __launch_bounds__(256) void p1_ln_deg(
    const float* __restrict__ nf, const float* __restrict__ g, const float* __restrict__ b,
    const ushort* __restrict__ WAhi, const ushort* __restrict__ WAlo,
    float* __restrict__ x, float* __restrict__ a_s, float* __restrict__ a_d,
    const int* __restrict__ ei, int* __restrict__ deg, int n, int E, int nblk1) {
    const int bp = blockIdx.x;
    if (bp < nblk1) {
        d_k1(bp, threadIdx.x, nf, g, b, WAhi, WAlo, x, a_s, a_d, n);
    } else {
        int e = (bp - nblk1) * 256 + threadIdx.x;
        if (e < E) atomicAdd(&deg[ei[E + e]], 1);
    }
}

// ---------------- K3a: per-4096-block inclusive scan + block totals ----------------
__global__ __launch_bounds__(1024) void k3a(const int* __restrict__ deg, int* __restrict__ incl,
                                            int* __restrict__ bsum, int n) {
    __shared__ int wsum[16];
    const int b = blockIdx.x, t = threadIdx.x;
    const int i0 = b * 4096 + t * 4;
    int4 v = make_int4(0, 0, 0, 0);
    if (i0 + 3 < n) v = *(const int4*)&deg[i0];
    else {
        int* vp = (int*)&v;
        for (int q = 0; q < 4; ++q) vp[q] = (i0 + q < n) ? deg[i0 + q] : 0;
    }
    const int s1 = v.x, s2 = s1 + v.y, s3 = s2 + v.z, s4 = s3 + v.w;
    const int lane = t & 63, wv = t >> 6;
    int xx = s4;
    #pragma unroll
    for (int off = 1; off < 64; off <<= 1) {
        int y = __shfl_up(xx, off);
        if (lane >= off) xx += y;
    }
    if (lane == 63) wsum[wv] = xx;
    __syncthreads();
    if (wv == 0) {
        int y = (lane < 16) ? wsum[lane] : 0;
        #pragma unroll
        for (int off = 1; off < 16; off <<= 1) {
            int z = __shfl_up(y, off);
            if (lane >= off) y += z;
        }
        if (lane < 16) wsum[lane] = y;
    }
    __syncthreads();
    const int wbase = (wv == 0) ? 0 : wsum[wv - 1];
    const int excl = xx - s4 + wbase;
    if (i0 < n) {
        int4 o = make_int4(excl + s1, excl + s2, excl + s3, excl + s4);
        if (i0 + 3 < n) *(int4*)&incl[i0] = o;
        else {
            int* op = (int*)&o;
            for (int q = 0; q < 4; ++q) if (i0 + q < n) incl[i0 + q] = op[q];
        }
    }
    if (t == 1023) bsum[b] = wbase + xx;
}

// ---------------- K3c: finalize row_ptr/cursor, inline 13-entry bsum scan ----------------
__global__ void k3c(const int* __restrict__ incl, const int* __restrict__ bsum,
                    const int* __restrict__ deg, int* __restrict__ row_ptr,
                    int* __restrict__ cursor, int n) {
    int i = blockIdx.x * blockDim.x + threadIdx.x;
    if (i < n) {
        int b = i >> 12;
        int base = 0;
        for (int q = 0; q < b; ++q) base += bsum[q];   // b <= 12, L2-hot
        int inc = incl[i] + base;
        row_ptr[i + 1] = inc;
        cursor[i] = inc - deg[i];
        if (i == 0) row_ptr[0] = 0;
    }
}

// ---------------- K4: scatter src ids into CSR ----------------
__global__ void k4_scatter(const int* __restrict__ ei, int* __restrict__ cursor,
                           int* __restrict__ col_src, int E) {
    int e = blockIdx.x * blockDim.x + threadIdx.x;
    if (e < E) {
        int dst = ei[E + e];
        int pos = atomicAdd(&cursor[dst], 1);
        col_src[pos] = ei[e];
    }
}

// ---------------- K5: per-dst online-softmax gather + residual + LN2 ----------------
__global__ __launch_bounds__(256) void k5_gather(
    const float* __restrict__ x, const float* __restrict__ a_s, const float* __restrict__ a_d,
    const int* __restrict__ row_ptr, const int* __restrict__ col_src,
    const float* __restrict__ nf, const float* __restrict__ bias_att,
    const float* __restrict__ ln2g, const float* __restrict__ ln2b,
    float* __restrict__ nf1, float* __restrict__ h2, int n) {
    const int w = (blockIdx.x * blockDim.x + threadIdx.x) >> 6;
    if (w >= n) return;
    const int lane = threadIdx.x & 63;
    const int h = lane >> 3;
    const int c0 = lane * 2;
    const float ad = a_d[w * HH + h];
    float e = a_s[w * HH + h] + ad;
    e = e > 0.f ? e : SLOPE * e;
    float m = e, denom = 1.f;
    float2 xv = *(const float2*)&x[(size_t)w * DD + c0];
    float acc0 = xv.x, acc1 = xv.y;
    const int beg = row_ptr[w], end = row_ptr[w + 1];
    int j = beg;
    const int j4end = beg + ((end - beg) & ~3);

#define BATCH_MATH(F0, F1, F2, F3, X0, X1, X2, X3) {                                   \
        float f0 = (F0) + ad, f1 = (F1) + ad, f2 = (F2) + ad, f3 = (F3) + ad;          \
        f0 = f0 > 0.f ? f0 : SLOPE * f0;  f1 = f1 > 0.f ? f1 : SLOPE * f1;             \
        f2 = f2 > 0.f ? f2 : SLOPE * f2;  f3 = f3 > 0.f ? f3 : SLOPE * f3;             \
        const float mb = fmaxf(fmaxf(f0, f1), fmaxf(f2, f3));                          \
        const float nm = fmaxf(m, mb);                                                 \
        const float sc = __expf(m - nm);                                               \
        const float p0 = __expf(f0 - nm), p1 = __expf(f1 - nm);                        \
        const float p2 = __expf(f2 - nm), p3 = __expf(f3 - nm);                        \
        denom = denom * sc + ((p0 + p1) + (p2 + p3));                                  \
        acc0 = acc0 * sc + (fmaf(X0.x, p0, X1.x * p1) + fmaf(X2.x, p2, X3.x * p3));    \
        acc1 = acc1 * sc + (fmaf(X0.y, p0, X1.y * p1) + fmaf(X2.y, p2, X3.y * p3));    \
        m = nm; }

    if (j < j4end) {
        int s0 = col_src[j], s1 = col_src[j + 1], s2 = col_src[j + 2], s3 = col_src[j + 3];
        float e0 = a_s[s0 * HH + h], e1 = a_s[s1 * HH + h];
        float e2 = a_s[s2 * HH + h], e3 = a_s[s3 * HH + h];
        float2 x0 = *(const float2*)&x[(size_t)s0 * DD + c0];
        float2 x1 = *(const float2*)&x[(size_t)s1 * DD + c0];
        float2 x2 = *(const float2*)&x[(size_t)s2 * DD + c0];
        float2 x3 = *(const float2*)&x[(size_t)s3 * DD + c0];
        for (j += 4;; j += 4) {
            const bool more = j < j4end;
            float ne0, ne1, ne2, ne3;
            float2 nx0, nx1, nx2, nx3;
            if (more) {
                const int t0 = col_src[j], t1 = col_src[j + 1];
                const int t2 = col_src[j + 2], t3 = col_src[j + 3];
                ne0 = a_s[t0 * HH + h]; ne1 = a_s[t1 * HH + h];
                ne2 = a_s[t2 * HH + h]; ne3 = a_s[t3 * HH + h];
                nx0 = *(const float2*)&x[(size_t)t0 * DD + c0];
                nx1 = *(const float2*)&x[(size_t)t1 * DD + c0];
                nx2 = *(const float2*)&x[(size_t)t2 * DD + c0];
                nx3 = *(const float2*)&x[(size_t)t3 * DD + c0];
            }
            BATCH_MATH(e0, e1, e2, e3, x0, x1, x2, x3)
            if (!more) break;
            e0 = ne0; e1 = ne1; e2 = ne2; e3 = ne3;
            x0 = nx0; x1 = nx1; x2 = nx2; x3 = nx3;
        }
    }
    for (; j < end; ++j) {
        const int s0 = col_src[j];
        float ev = a_s[s0 * HH + h] + ad;
        ev = ev > 0.f ? ev : SLOPE * ev;
        const float2 x0 = *(const float2*)&x[(size_t)s0 * DD + c0];
        const float nm = fmaxf(m, ev);
        const float sc = __expf(m - nm);
        const float pp = __expf(ev - nm);
        denom = denom * sc + pp;
        acc0 = acc0 * sc + x0.x * pp;
        acc1 = acc1 * sc + x0.y * pp;
        m = nm;
    }
#undef BATCH_MATH
    const float inv = 1.f / (denom + 1e-16f);
    float o0 = acc0 * inv + bias_att[c0]     + nf[(size_t)w * DD + c0];
    float o1 = acc1 * inv + bias_att[c0 + 1] + nf[(size_t)w * DD + c0 + 1];
    *(float2*)&nf1[(size_t)w * DD + c0] = make_float2(o0, o1);
    float s = o0 + o1;
    #pragma unroll
    for (int o = 32; o >= 1; o >>= 1) s += __shfl_xor(s, o);
    const float mean = s * (1.f / DD);
    const float d0 = o0 - mean, d1 = o1 - mean;
    float q = d0 * d0 + d1 * d1;
    #pragma unroll
    for (int o = 32; o >= 1; o >>= 1) q += __shfl_xor(q, o);
    const float var = q * (1.f / (DD - 1));
    const float iv = 1.f / (sqrtf(var) + EPS);
    float z0 = ln2g[c0] * d0 * iv + ln2b[c0];
    float z1 = ln2g[c0 + 1] * d1 * iv + ln2b[c0 + 1];
    *(float2*)&h2[(size_t)w * DD + c0] = make_float2(z0, z1);
}

// ---------------- K6: split-bf16 MFMA FFN, TM=128, 8 waves, 2-phase dbuf pipeline ----------------
// Frag-order weights, conflict-free LDS reads. Grid 391 < resident capacity -> all blocks
// start immediately; 16 waves/CU. Per chunk: prefetch next to regs -> compute -> barrier ->
// ds_write -> barrier.
__global__ __launch_bounds__(512, 4) void k6_mfma(
    const float* __restrict__ h2, const float* __restrict__ nf1,
    const ushort* __restrict__ W1Fhi, const ushort* __restrict__ W1Flo,
    const ushort* __restrict__ W2Fhi, const ushort* __restrict__ W2Flo,
    const float* __restrict__ b1, const float* __restrict__ b2,
    float* __restrict__ out, int n) {
    __shared__ ushort buf[2][16384];   // 64KB: [W1hi 8KB | W1lo 8KB | W2hi 8KB | W2lo 8KB] x2
    __shared__ float hhs[4096];        // 16KB: 8 waves x [16 nodes][32 ff] swizzled
    const int tid = threadIdx.x;
    const int w = tid >> 6, l = tid & 63;
    const int l15 = l & 15, l4 = l >> 4;
    const int nbase = blockIdx.x * TM6;
    char* hw = (char*)hhs + w * 2048;

    // ---- A-frags: this wave's 16 node rows of h2, split into hi/lo bf16
    int arow = nbase + w * 16 + l15;
    if (arow >= n) arow = n - 1;                    // clamp; tail writes guarded
    const float* ap = h2 + (size_t)arow * DD + l4 * 8;
    bf16x8 Ahi[4], Alo[4];
    #pragma unroll
    for (int s = 0; s < 4; ++s) {
        float v[8];
        *(float4*)&v[0] = *(const float4*)(ap + s * 32);
        *(float4*)&v[4] = *(const float4*)(ap + s * 32 + 4);
        bf16x8 hv, lv;
        #pragma unroll
        for (int jj = 0; jj < 8; ++jj) {
            ushort hb = f2bf(v[jj]);
            hv[jj] = (short)hb;
            lv[jj] = (short)f2bf(v[jj] - bf2f(hb));
        }
        Ahi[s] = hv; Alo[s] = lv;
    }

    f32x4 acc_o[8];
    #pragma unroll
    for (int oc = 0; oc < 8; ++oc) acc_o[oc] = (f32x4){0.f, 0.f, 0.f, 0.f};

    // ---- prologue: stage chunk 0 into buf[0] (512 threads x 16B per plane)
    {
        const int o8 = tid * 8, o16 = tid * 16;
        *(bf16x8*)((char*)buf + 0     + o16) = *(const bf16x8*)(W1Fhi + o8);
        *(bf16x8*)((char*)buf + 8192  + o16) = *(const bf16x8*)(W1Flo + o8);
        *(bf16x8*)((char*)buf + 16384 + o16) = *(const bf16x8*)(W2Fhi + o8);
        *(bf16x8*)((char*)buf + 24576 + o16) = *(const bf16x8*)(W2Flo + o8);
    }
    __syncthreads();

    int cur = 0;
    #pragma unroll 1
    for (int ch = 0; ch < 16; ++ch) {
        // ---- issue next-chunk global loads (consumed after the compute phase)
        bf16x8 st[4];
        if (ch < 15) {
            const int o8 = (ch + 1) * 4096 + tid * 8;
            st[0] = *(const bf16x8*)(W1Fhi + o8);
            st[1] = *(const bf16x8*)(W1Flo + o8);
            st[2] = *(const bf16x8*)(W2Fhi + o8);
            st[3] = *(const bf16x8*)(W2Flo + o8);
        }
        const char* cb = (const char*)buf + cur;
        // ---- stage A: hh[16 nodes][32 ff] = relu(h2 @ W1_chunk + b1)
        #pragma unroll
        for (int tc = 0; tc < 2; ++tc) {
            f32x4 a = (f32x4){0.f, 0.f, 0.f, 0.f};
            #pragma unroll
            for (int s = 0; s < 4; ++s) {
                const int fo = ((tc * 4 + s) * 64 + l) * 16;
                bf16x8 bh = *(const bf16x8*)(cb + fo);
                bf16x8 bl = *(const bf16x8*)(cb + 8192 + fo);
                a = __builtin_amdgcn_mfma_f32_16x16x32_bf16(Ahi[s], bh, a, 0, 0, 0);
                a = __builtin_amdgcn_mfma_f32_16x16x32_bf16(Alo[s], bh, a, 0, 0, 0);
                a = __builtin_amdgcn_mfma_f32_16x16x32_bf16(Ahi[s], bl, a, 0, 0, 0);
            }
            const float bias = b1[ch * 32 + tc * 16 + l15];
            #pragma unroll
            for (int i = 0; i < 4; ++i) {
                const int row = l4 * 4 + i;
                const int byte = (row * 128 + (tc * 16 + l15) * 4) ^ ((row & 7) << 4);
                *(float*)(hw + byte) = fmaxf(a[i] + bias, 0.f);
            }
        }
        // ---- transpose read-back (wave-private; lgkmcnt ordering, no barrier)
        bf16x8 Phi, Plo;
        {
            const int base = (l15 * 128 + l4 * 32);
            const int msk = (l15 & 7) << 4;
            float v[8];
            *(float4*)&v[0] = *(const float4*)(hw + (base ^ msk));
            *(float4*)&v[4] = *(const float4*)(hw + ((base + 16) ^ msk));
            #pragma unroll
            for (int jj = 0; jj < 8; ++jj) {
                ushort hb = f2bf(v[jj]);
                Phi[jj] = (short)hb;
                Plo[jj] = (short)f2bf(v[jj] - bf2f(hb));
            }
        }
        // ---- stage B: acc_o += hh @ W2_chunk
        #pragma unroll
        for (int oc = 0; oc < 8; ++oc) {
            const int fo = (oc * 64 + l) * 16;
            bf16x8 bh = *(const bf16x8*)(cb + 16384 + fo);
            bf16x8 bl = *(const bf16x8*)(cb + 24576 + fo);
            acc_o[oc] = __builtin_amdgcn_mfma_f32_16x16x32_bf16(Phi, bh, acc_o[oc], 0, 0, 0);
            acc_o[oc] = __builtin_amdgcn_mfma_f32_16x16x32_bf16(Plo, bh, acc_o[oc], 0, 0, 0);
            acc_o[oc] = __builtin_amdgcn_mfma_f32_16x16x32_bf16(Phi, bl, acc_o[oc], 0, 0, 0);
        }
        __syncthreads();                   // all waves done reading buf[cur]
        if (ch < 15) {
            char* db = (char*)buf + (cur ^ 32768);
            const int o16 = tid * 16;
            *(bf16x8*)(db + 0     + o16) = st[0];
            *(bf16x8*)(db + 8192  + o16) = st[1];
            *(bf16x8*)(db + 16384 + o16) = st[2];
            *(bf16x8*)(db + 24576 + o16) = st[3];
            __syncthreads();               // next buffer visible
            cur ^= 32768;
        }
    }
    // ---- epilogue: + b2 + residual
    #pragma unroll
    for (int oc = 0; oc < 8; ++oc) {
        const int col = oc * 16 + l15;
        const float b2v = b2[col];
        #pragma unroll
        for (int i = 0; i < 4; ++i) {
            const int node = nbase + w * 16 + l4 * 4 + i;
            if (node < n)
                out[(size_t)node * DD + col] = acc_o[oc][i] + b2v + nf1[(size_t)node * DD + col];
        }
    }
}

extern "C" void kernel_launch(void* const* d_in, const int* in_sizes, int n_in,
                              void* d_out, int out_size, void* d_ws, size_t ws_size,
                              hipStream_t stream) {
    const float* nf       = (const float*)d_in[0];
    const int*   ei       = (const int*)d_in[1];
    const float* ln1_g    = (const float*)d_in[2];
    const float* ln1_b    = (const float*)d_in[3];
    const float* W_att    = (const float*)d_in[4];
    const float* att_src  = (const float*)d_in[5];
    const float* att_dst  = (const float*)d_in[6];
    const float* bias_att = (const float*)d_in[7];
    const float* ln2_g    = (const float*)d_in[8];
    const float* ln2_b    = (const float*)d_in[9];
    const float* W1       = (const float*)d_in[10];
    const float* b1       = (const float*)d_in[11];
    const float* W2       = (const float*)d_in[12];
    const float* b2       = (const float*)d_in[13];
    const int n = in_sizes[0] / DD;
    const int E = in_sizes[1] / 2;

    char* ws = (char*)d_ws;
    size_t off = 0;
    auto alloc = [&](size_t bytes) {
        off = (off + 255) & ~(size_t)255;
        char* p = ws + off;
        off += bytes;
        return p;
    };
    float*  x       = (float*)alloc((size_t)n * DD * 4);
    float*  a_s     = (float*)alloc((size_t)n * HH * 4);
    float*  a_d     = (float*)alloc((size_t)n * HH * 4);
    float*  nf1     = (float*)alloc((size_t)n * DD * 4);
    float*  h2      = (float*)alloc((size_t)n * DD * 4);
    int*    row_ptr = (int*)alloc((size_t)(n + 1) * 4);
    int*    cursor  = (int*)alloc((size_t)n * 4);
    int*    deg     = (int*)alloc((size_t)n * 4);
    int*    incl    = (int*)alloc((size_t)n * 4);
    int*    bsum    = (int*)alloc(64 * 4);
    int*    col_src = (int*)alloc((size_t)E * 4);
    ushort* WAhi    = (ushort*)alloc((size_t)144 * DD * 2);   // [W_att^T | Was | Wad]
    ushort* WAlo    = (ushort*)alloc((size_t)144 * DD * 2);
    ushort* W1Fhi   = (ushort*)alloc((size_t)DFF * DD * 2);   // frag-order planes
    ushort* W1Flo   = (ushort*)alloc((size_t)DFF * DD * 2);
    ushort* W2Fhi   = (ushort*)alloc((size_t)DD * DFF * 2);
    ushort* W2Flo   = (ushort*)alloc((size_t)DD * DFF * 2);
    (void)ws_size; (void)n_in; (void)out_size;

    const int nb3   = (n + 4095) / 4096;
    const int nblk1 = (n + TM - 1) / TM;                  // k1 blocks
    const int nblk2 = (E + 255) / 256;                    // k2 blocks
    const int nblk0 = 81 + (n + 255) / 256;               // prep blocks

    p0_prep<<<nblk0, 256, 0, stream>>>(W_att, att_src, att_dst, W1, W2,
                                       WAhi, WAlo, W1Fhi, W1Flo, W2Fhi, W2Flo, deg, n);
    p1_ln_deg<<<nblk1 + nblk2, 256, 0, stream>>>(nf, ln1_g, ln1_b, WAhi, WAlo,
                                                 x, a_s, a_d, ei, deg, n, E, nblk1);
    k3a<<<nb3, 1024, 0, stream>>>(deg, incl, bsum, n);
    k3c<<<(n + 255) / 256, 256, 0, stream>>>(incl, bsum, deg, row_ptr, cursor, n);
    k4_scatter<<<nblk2, 256, 0, stream>>>(ei, cursor, col_src, E);
    k5_gather<<<(n + 3) / 4, 256, 0, stream>>>(x, a_s, a_d, row_ptr, col_src, nf, bias_att,
                                               ln2_g, ln2_b, nf1, h2, n);
    k6_mfma<<<(n + TM6 - 1) / TM6, 512, 0, stream>>>(h2, nf1, W1Fhi, W1Flo, W2Fhi, W2Flo,
                                                     b1, b2, (float*)d_out, n);
}

// Round 8
// 329.969 us; speedup vs baseline: 1.7394x; 1.0737x over previous
//
#include <hip/hip_runtime.h>

#define DD 128
#define HH 8
#define DFF 512
#define EPS 1e-6f
#define SLOPE 0.2f
#define LOG2E 1.4426950408889634f
#define TM 64
#define TM6 128

typedef float f32x4 __attribute__((ext_vector_type(4)));
typedef short bf16x8 __attribute__((ext_vector_type(8)));

__device__ __forceinline__ ushort f2bf(float f) {
    unsigned u = __float_as_uint(f);
    return (ushort)((u + 0x7FFFu + ((u >> 16) & 1u)) >> 16);   // RNE
}
__device__ __forceinline__ float bf2f(ushort h) {
    return __uint_as_float(((unsigned)h) << 16);
}

// ================= P0: fused prep (kzero | ksplitT(W_att) | kattw | kfrag1 | kfrag2) ==========
__device__ void d_splitT(int bp, int tid, const float* __restrict__ src,
                         ushort* __restrict__ hi, ushort* __restrict__ lo, int R, int C) {
    __shared__ float tile[32][33];
    const int tc = (bp & 3) * 32, tr = (bp >> 2) * 32;
    const int lx = tid & 31, ly = tid >> 5;            // 32 x 8
    for (int i = 0; i < 32; i += 8) {
        int r = tr + ly + i, c = tc + lx;
        tile[ly + i][lx] = (r < R && c < C) ? src[(size_t)r * C + c] : 0.f;
    }
    __syncthreads();
    for (int i = 0; i < 32; i += 8) {
        int c = tc + ly + i, r = tr + lx;
        if (c < C && r < R) {
            float f = tile[lx][ly + i];
            ushort h = f2bf(f);
            hi[(size_t)c * R + r] = h;
            lo[(size_t)c * R + r] = f2bf(f - bf2f(h));
        }
    }
}

__device__ void d_attw(int tid, const float* __restrict__ W, const float* __restrict__ asrc,
                       const float* __restrict__ adst, ushort* __restrict__ hi,
                       ushort* __restrict__ lo) {
    if (tid >= DD) return;
    const int k = tid;
    for (int h = 0; h < HH; ++h) {
        float s1 = 0.f, s2 = 0.f;
        #pragma unroll
        for (int dh = 0; dh < 16; ++dh) {
            float w = W[k * DD + h * 16 + dh];
            s1 = fmaf(w, asrc[h * 16 + dh], s1);
            s2 = fmaf(w, adst[h * 16 + dh], s2);
        }
        s1 *= LOG2E;   // fold log2e: k5 softmax runs in exp2 domain (leaky_relu commutes, softmax invariant)
        s2 *= LOG2E;
        ushort h1 = f2bf(s1);
        hi[(128 + h) * DD + k] = h1;
        lo[(128 + h) * DD + k] = f2bf(s1 - bf2f(h1));
        ushort h2 = f2bf(s2);
        hi[(136 + h) * DD + k] = h2;
        lo[(136 + h) * DD + k] = f2bf(s2 - bf2f(h2));
    }
}

__device__ void d_frag1(int bp, int tid, const float* __restrict__ W1,
                        ushort* __restrict__ hi, ushort* __restrict__ lo) {
    const int f = bp * 256 + tid;                      // 8192 frags
    const int l = f & 63, s = (f >> 6) & 3, tc = (f >> 8) & 1, ch = f >> 9;
    const int ff = ch * 32 + tc * 16 + (l & 15);
    const int k0 = s * 32 + (l >> 4) * 8;
    #pragma unroll
    for (int j = 0; j < 8; ++j) {
        float w = W1[(size_t)(k0 + j) * DFF + ff];
        ushort h = f2bf(w);
        hi[f * 8 + j] = h;
        lo[f * 8 + j] = f2bf(w - bf2f(h));
    }
}

__device__ void d_frag2(int bp, int tid, const float* __restrict__ W2,
                        ushort* __restrict__ hi, ushort* __restrict__ lo) {
    const int f = bp * 256 + tid;                      // 8192 frags
    const int l = f & 63, oc = (f >> 6) & 7, ch = f >> 9;
    const int out = oc * 16 + (l & 15);
    const int k0 = ch * 32 + (l >> 4) * 8;
    #pragma unroll
    for (int j = 0; j < 8; ++j) {
        float w = W2[(size_t)(k0 + j) * DD + out];
        ushort h = f2bf(w);
        hi[f * 8 + j] = h;
        lo[f * 8 + j] = f2bf(w - bf2f(h));
    }
}

__global__ __launch_bounds__(256) void p0_prep(
    const float* __restrict__ W_att, const float* __restrict__ asrc,
    const float* __restrict__ adst, const float* __restrict__ W1, const float* __restrict__ W2,
    ushort* __restrict__ WAhi, ushort* __restrict__ WAlo,
    ushort* __restrict__ W1Fhi, ushort* __restrict__ W1Flo,
    ushort* __restrict__ W2Fhi, ushort* __restrict__ W2Flo,
    int* __restrict__ deg, int n) {
    const int bp = blockIdx.x, tid = threadIdx.x;
    if (bp < 16)            d_splitT(bp, tid, W_att, WAhi, WAlo, DD, DD);
    else if (bp == 16)      d_attw(tid, W_att, asrc, adst, WAhi, WAlo);
    else if (bp < 49)       d_frag1(bp - 17, tid, W1, W1Fhi, W1Flo);
    else if (bp < 81)       d_frag2(bp - 49, tid, W2, W2Fhi, W2Flo);
    else {
        int i = (bp - 81) * 256 + tid;
        if (i < n) deg[i] = 0;
    }
}

// ================= P1: fused k1_mfma | k2_deg (independent work, concurrent) =================
__device__ void d_k1(int bid, int tid,
                     const float* __restrict__ nf, const float* __restrict__ g,
                     const float* __restrict__ b, const ushort* __restrict__ WAhi,
                     const ushort* __restrict__ WAlo, ushort* __restrict__ xb,
                     float* __restrict__ a_s, float* __restrict__ a_d, int n) {
    const int w = tid >> 6, l = tid & 63;
    const int l15 = l & 15, l4 = l >> 4;
    const int nbase = bid * TM;
    int arow = nbase + w * 16 + l15;
    if (arow >= n) arow = n - 1;

    float v[4][8];
    const float* ap = nf + (size_t)arow * DD + l4 * 8;
    #pragma unroll
    for (int s = 0; s < 4; ++s) {
        *(float4*)&v[s][0] = *(const float4*)(ap + s * 32);
        *(float4*)&v[s][4] = *(const float4*)(ap + s * 32 + 4);
    }
    float sum = 0.f;
    #pragma unroll
    for (int s = 0; s < 4; ++s)
        #pragma unroll
        for (int j = 0; j < 8; ++j) sum += v[s][j];
    sum += __shfl_xor(sum, 16);
    sum += __shfl_xor(sum, 32);
    const float mean = sum * (1.f / DD);
    float qs = 0.f;
    #pragma unroll
    for (int s = 0; s < 4; ++s)
        #pragma unroll
        for (int j = 0; j < 8; ++j) { float d = v[s][j] - mean; qs += d * d; }
    qs += __shfl_xor(qs, 16);
    qs += __shfl_xor(qs, 32);
    const float iv = 1.f / (sqrtf(qs * (1.f / (DD - 1))) + EPS);

    bf16x8 Ahi[4], Alo[4];
    #pragma unroll
    for (int s = 0; s < 4; ++s) {
        const int k0 = s * 32 + l4 * 8;
        float gv[8], bv[8];
        *(float4*)&gv[0] = *(const float4*)(g + k0);
        *(float4*)&gv[4] = *(const float4*)(g + k0 + 4);
        *(float4*)&bv[0] = *(const float4*)(b + k0);
        *(float4*)&bv[4] = *(const float4*)(b + k0 + 4);
        bf16x8 hv, lv;
        #pragma unroll
        for (int j = 0; j < 8; ++j) {
            float f = fmaf(gv[j], (v[s][j] - mean) * iv, bv[j]);
            ushort hb = f2bf(f);
            hv[j] = (short)hb;
            lv[j] = (short)f2bf(f - bf2f(hb));
        }
        Ahi[s] = hv; Alo[s] = lv;
    }

    #pragma unroll
    for (int oc = 0; oc < 9; ++oc) {
        f32x4 acc = (f32x4){0.f, 0.f, 0.f, 0.f};
        const ushort* bp = WAhi + (size_t)(oc * 16 + l15) * DD + l4 * 8;
        const ushort* lp = WAlo + (size_t)(oc * 16 + l15) * DD + l4 * 8;
        #pragma unroll
        for (int s = 0; s < 4; ++s) {
            bf16x8 bh = *(const bf16x8*)(bp + s * 32);
            bf16x8 bl = *(const bf16x8*)(lp + s * 32);
            acc = __builtin_amdgcn_mfma_f32_16x16x32_bf16(Ahi[s], bh, acc, 0, 0, 0);
            acc = __builtin_amdgcn_mfma_f32_16x16x32_bf16(Alo[s], bh, acc, 0, 0, 0);
            acc = __builtin_amdgcn_mfma_f32_16x16x32_bf16(Ahi[s], bl, acc, 0, 0, 0);
        }
        #pragma unroll
        for (int i = 0; i < 4; ++i) {
            const int node = nbase + w * 16 + l4 * 4 + i;
            if (node < n) {
                if (oc < 8) xb[(size_t)node * DD + oc * 16 + l15] = f2bf(acc[i]);
                else if (l15 < 8) a_s[node * HH + l15] = acc[i];
                else a_d[node * HH + (l15 - 8)] = acc[i];
            }
        }
    }
}

__global__ __launch_bounds__(256) void p1_ln_deg(
    const float* __restrict__ nf, const float* __restrict__ g, const float* __restrict__ b,
    const ushort* __restrict__ WAhi, const ushort* __restrict__ WAlo,
    ushort* __restrict__ xb, float* __restrict__ a_s, float* __restrict__ a_d,
    const int* __restrict__ ei, int* __restrict__ deg, int n, int E, int nblk1) {
    const int bp = blockIdx.x;
    if (bp < nblk1) {
        d_k1(bp, threadIdx.x, nf, g, b, WAhi, WAlo, xb, a_s, a_d, n);
    } else {
        int e = (bp - nblk1) * 256 + threadIdx.x;
        if (e < E) atomicAdd(&deg[ei[E + e]], 1);
    }
}

// ---------------- K3a: per-4096-block inclusive scan + block totals ----------------
__global__ __launch_bounds__(1024) void k3a(const int* __restrict__ deg, int* __restrict__ incl,
                                            int* __restrict__ bsum, int n) {
    __shared__ int wsum[16];
    const int b = blockIdx.x, t = threadIdx.x;
    const int i0 = b * 4096 + t * 4;
    int4 v = make_int4(0, 0, 0, 0);
    if (i0 + 3 < n) v = *(const int4*)&deg[i0];
    else {
        int* vp = (int*)&v;
        for (int q = 0; q < 4; ++q) vp[q] = (i0 + q < n) ? deg[i0 + q] : 0;
    }
    const int s1 = v.x, s2 = s1 + v.y, s3 = s2 + v.z, s4 = s3 + v.w;
    const int lane = t & 63, wv = t >> 6;
    int xx = s4;
    #pragma unroll
    for (int off = 1; off < 64; off <<= 1) {
        int y = __shfl_up(xx, off);
        if (lane >= off) xx += y;
    }
    if (lane == 63) wsum[wv] = xx;
    __syncthreads();
    if (wv == 0) {
        int y = (lane < 16) ? wsum[lane] : 0;
        #pragma unroll
        for (int off = 1; off < 16; off <<= 1) {
            int z = __shfl_up(y, off);
            if (lane >= off) y += z;
        }
        if (lane < 16) wsum[lane] = y;
    }
    __syncthreads();
    const int wbase = (wv == 0) ? 0 : wsum[wv - 1];
    const int excl = xx - s4 + wbase;
    if (i0 < n) {
        int4 o = make_int4(excl + s1, excl + s2, excl + s3, excl + s4);
        if (i0 + 3 < n) *(int4*)&incl[i0] = o;
        else {
            int* op = (int*)&o;
            for (int q = 0; q < 4; ++q) if (i0 + q < n) incl[i0 + q] = op[q];
        }
    }
    if (t == 1023) bsum[b] = wbase + xx;
}

// ---------------- K3c: finalize row_ptr/cursor, inline 13-entry bsum scan ----------------
__global__ void k3c(const int* __restrict__ incl, const int* __restrict__ bsum,
                    const int* __restrict__ deg, int* __restrict__ row_ptr,
                    int* __restrict__ cursor, int n) {
    int i = blockIdx.x * blockDim.x + threadIdx.x;
    if (i < n) {
        int b = i >> 12;
        int base = 0;
        for (int q = 0; q < b; ++q) base += bsum[q];   // b <= 12, L2-hot
        int inc = incl[i] + base;
        row_ptr[i + 1] = inc;
        cursor[i] = inc - deg[i];
        if (i == 0) row_ptr[0] = 0;
    }
}

// ---------------- K4: scatter src ids into CSR ----------------
__global__ void k4_scatter(const int* __restrict__ ei, int* __restrict__ cursor,
                           int* __restrict__ col_src, int E) {
    int e = blockIdx.x * blockDim.x + threadIdx.x;
    if (e < E) {
        int dst = ei[E + e];
        int pos = atomicAdd(&cursor[dst], 1);
        col_src[pos] = ei[e];
    }
}

// ---------------- K5: per-dst online-softmax gather (bf16 payload, exp2 domain) ----------------
__global__ __launch_bounds__(256) void k5_gather(
    const ushort* __restrict__ xb, const float* __restrict__ a_s, const float* __restrict__ a_d,
    const int* __restrict__ row_ptr, const int* __restrict__ col_src,
    const float* __restrict__ nf, const float* __restrict__ bias_att,
    const float* __restrict__ ln2g, const float* __restrict__ ln2b,
    float* __restrict__ nf1, float* __restrict__ h2, int n) {
    const int w = (blockIdx.x * blockDim.x + threadIdx.x) >> 6;
    if (w >= n) return;
    const int lane = threadIdx.x & 63;
    const int h = lane >> 3;
    const int c0 = lane * 2;
    const float ad = a_d[w * HH + h];
    float e = a_s[w * HH + h] + ad;      // already log2e-scaled (prep fold)
    e = e > 0.f ? e : SLOPE * e;
    float m = e, denom = 1.f;
    const uint xw = *(const uint*)&xb[(size_t)w * DD + c0];
    float acc0 = __uint_as_float(xw << 16);
    float acc1 = __uint_as_float(xw & 0xFFFF0000u);
    const int beg = row_ptr[w], end = row_ptr[w + 1];
    int j = beg;
    const int j4end = beg + ((end - beg) & ~3);

#define BATCH_MATH(F0, F1, F2, F3, U0, U1, U2, U3) {                                   \
        float f0 = (F0) + ad, f1 = (F1) + ad, f2 = (F2) + ad, f3 = (F3) + ad;          \
        f0 = f0 > 0.f ? f0 : SLOPE * f0;  f1 = f1 > 0.f ? f1 : SLOPE * f1;             \
        f2 = f2 > 0.f ? f2 : SLOPE * f2;  f3 = f3 > 0.f ? f3 : SLOPE * f3;             \
        const float mb = fmaxf(fmaxf(f0, f1), fmaxf(f2, f3));                          \
        const float nm = fmaxf(m, mb);                                                 \
        const float sc = exp2f(m - nm);                                                \
        const float p0 = exp2f(f0 - nm), p1 = exp2f(f1 - nm);                          \
        const float p2 = exp2f(f2 - nm), p3 = exp2f(f3 - nm);                          \
        denom = denom * sc + ((p0 + p1) + (p2 + p3));                                  \
        acc0 = acc0 * sc + (fmaf(__uint_as_float((U0) << 16), p0,                      \
                                 __uint_as_float((U1) << 16) * p1)                     \
                          + fmaf(__uint_as_float((U2) << 16), p2,                      \
                                 __uint_as_float((U3) << 16) * p3));                   \
        acc1 = acc1 * sc + (fmaf(__uint_as_float((U0) & 0xFFFF0000u), p0,              \
                                 __uint_as_float((U1) & 0xFFFF0000u) * p1)             \
                          + fmaf(__uint_as_float((U2) & 0xFFFF0000u), p2,              \
                                 __uint_as_float((U3) & 0xFFFF0000u) * p3));           \
        m = nm; }

    if (j < j4end) {
        int s0 = col_src[j], s1 = col_src[j + 1], s2 = col_src[j + 2], s3 = col_src[j + 3];
        float e0 = a_s[s0 * HH + h], e1 = a_s[s1 * HH + h];
        float e2 = a_s[s2 * HH + h], e3 = a_s[s3 * HH + h];
        uint x0 = *(const uint*)&xb[(size_t)s0 * DD + c0];
        uint x1 = *(const uint*)&xb[(size_t)s1 * DD + c0];
        uint x2 = *(const uint*)&xb[(size_t)s2 * DD + c0];
        uint x3 = *(const uint*)&xb[(size_t)s3 * DD + c0];
        for (j += 4;; j += 4) {
            const bool more = j < j4end;
            float ne0, ne1, ne2, ne3;
            uint nx0, nx1, nx2, nx3;
            if (more) {   // issue next-batch loads before current-batch math
                const int t0 = col_src[j], t1 = col_src[j + 1];
                const int t2 = col_src[j + 2], t3 = col_src[j + 3];
                ne0 = a_s[t0 * HH + h]; ne1 = a_s[t1 * HH + h];
                ne2 = a_s[t2 * HH + h]; ne3 = a_s[t3 * HH + h];
                nx0 = *(const uint*)&xb[(size_t)t0 * DD + c0];
                nx1 = *(const uint*)&xb[(size_t)t1 * DD + c0];
                nx2 = *(const uint*)&xb[(size_t)t2 * DD + c0];
                nx3 = *(const uint*)&xb[(size_t)t3 * DD + c0];
            }
            BATCH_MATH(e0, e1, e2, e3, x0, x1, x2, x3)
            if (!more) break;
            e0 = ne0; e1 = ne1; e2 = ne2; e3 = ne3;
            x0 = nx0; x1 = nx1; x2 = nx2; x3 = nx3;
        }
    }
    for (; j < end; ++j) {
        const int s0 = col_src[j];
        float ev = a_s[s0 * HH + h] + ad;
        ev = ev > 0.f ? ev : SLOPE * ev;
        const uint x0 = *(const uint*)&xb[(size_t)s0 * DD + c0];
        const float nm = fmaxf(m, ev);
        const float sc = exp2f(m - nm);
        const float pp = exp2f(ev - nm);
        denom = denom * sc + pp;
        acc0 = acc0 * sc + __uint_as_float(x0 << 16) * pp;
        acc1 = acc1 * sc + __uint_as_float(x0 & 0xFFFF0000u) * pp;
        m = nm;
    }
#undef BATCH_MATH
    const float inv = 1.f / (denom + 1e-16f);
    float o0 = acc0 * inv + bias_att[c0]     + nf[(size_t)w * DD + c0];
    float o1 = acc1 * inv + bias_att[c0 + 1] + nf[(size_t)w * DD + c0 + 1];
    *(float2*)&nf1[(size_t)w * DD + c0] = make_float2(o0, o1);
    float s = o0 + o1;
    #pragma unroll
    for (int o = 32; o >= 1; o >>= 1) s += __shfl_xor(s, o);
    const float mean = s * (1.f / DD);
    const float d0 = o0 - mean, d1 = o1 - mean;
    float q = d0 * d0 + d1 * d1;
    #pragma unroll
    for (int o = 32; o >= 1; o >>= 1) q += __shfl_xor(q, o);
    const float var = q * (1.f / (DD - 1));
    const float iv = 1.f / (sqrtf(var) + EPS);
    float z0 = ln2g[c0] * d0 * iv + ln2b[c0];
    float z1 = ln2g[c0 + 1] * d1 * iv + ln2b[c0 + 1];
    *(float2*)&h2[(size_t)w * DD + c0] = make_float2(z0, z1);
}

// ---------------- K6: split-bf16 MFMA FFN, TM=128, 8 waves, 2-phase dbuf pipeline ----------------
__global__ __launch_bounds__(512, 4) void k6_mfma(
    const float* __restrict__ h2, const float* __restrict__ nf1,
    const ushort* __restrict__ W1Fhi, const ushort* __restrict__ W1Flo,
    const ushort* __restrict__ W2Fhi, const ushort* __restrict__ W2Flo,
    const float* __restrict__ b1, const float* __restrict__ b2,
    float* __restrict__ out, int n) {
    __shared__ ushort buf[2][16384];   // 64KB: [W1hi 8KB | W1lo 8KB | W2hi 8KB | W2lo 8KB] x2
    __shared__ float hhs[4096];        // 16KB: 8 waves x [16 nodes][32 ff] swizzled
    const int tid = threadIdx.x;
    const int w = tid >> 6, l = tid & 63;
    const int l15 = l & 15, l4 = l >> 4;
    const int nbase = blockIdx.x * TM6;
    char* hw = (char*)hhs + w * 2048;

    // ---- A-frags: this wave's 16 node rows of h2, split into hi/lo bf16
    int arow = nbase + w * 16 + l15;
    if (arow >= n) arow = n - 1;                    // clamp; tail writes guarded
    const float* ap = h2 + (size_t)arow * DD + l4 * 8;
    bf16x8 Ahi[4], Alo[4];
    #pragma unroll
    for (int s = 0; s < 4; ++s) {
        float v[8];
        *(float4*)&v[0] = *(const float4*)(ap + s * 32);
        *(float4*)&v[4] = *(const float4*)(ap + s * 32 + 4);
        bf16x8 hv, lv;
        #pragma unroll
        for (int jj = 0; jj < 8; ++jj) {
            ushort hb = f2bf(v[jj]);
            hv[jj] = (short)hb;
            lv[jj] = (short)f2bf(v[jj] - bf2f(hb));
        }
        Ahi[s] = hv; Alo[s] = lv;
    }

    f32x4 acc_o[8];
    #pragma unroll
    for (int oc = 0; oc < 8; ++oc) acc_o[oc] = (f32x4){0.f, 0.f, 0.f, 0.f};

    // ---- prologue: stage chunk 0 into buf[0] (512 threads x 16B per plane)
    {
        const int o8 = tid * 8, o16 = tid * 16;
        *(bf16x8*)((char*)buf + 0     + o16) = *(const bf16x8*)(W1Fhi + o8);
        *(bf16x8*)((char*)buf + 8192  + o16) = *(const bf16x8*)(W1Flo + o8);
        *(bf16x8*)((char*)buf + 16384 + o16) = *(const bf16x8*)(W2Fhi + o8);
        *(bf16x8*)((char*)buf + 24576 + o16) = *(const bf16x8*)(W2Flo + o8);
    }
    __syncthreads();

    int cur = 0;
    #pragma unroll 1
    for (int ch = 0; ch < 16; ++ch) {
        // ---- issue next-chunk global loads (consumed after the compute phase)
        bf16x8 st[4];
        if (ch < 15) {
            const int o8 = (ch + 1) * 4096 + tid * 8;
            st[0] = *(const bf16x8*)(W1Fhi + o8);
            st[1] = *(const bf16x8*)(W1Flo + o8);
            st[2] = *(const bf16x8*)(W2Fhi + o8);
            st[3] = *(const bf16x8*)(W2Flo + o8);
        }
        const char* cb = (const char*)buf + cur;
        // ---- stage A: hh[16 nodes][32 ff] = relu(h2 @ W1_chunk + b1)
        #pragma unroll
        for (int tc = 0; tc < 2; ++tc) {
            f32x4 a = (f32x4){0.f, 0.f, 0.f, 0.f};
            #pragma unroll
            for (int s = 0; s < 4; ++s) {
                const int fo = ((tc * 4 + s) * 64 + l) * 16;
                bf16x8 bh = *(const bf16x8*)(cb + fo);
                bf16x8 bl = *(const bf16x8*)(cb + 8192 + fo);
                a = __builtin_amdgcn_mfma_f32_16x16x32_bf16(Ahi[s], bh, a, 0, 0, 0);
                a = __builtin_amdgcn_mfma_f32_16x16x32_bf16(Alo[s], bh, a, 0, 0, 0);
                a = __builtin_amdgcn_mfma_f32_16x16x32_bf16(Ahi[s], bl, a, 0, 0, 0);
            }
            const float bias = b1[ch * 32 + tc * 16 + l15];
            #pragma unroll
            for (int i = 0; i < 4; ++i) {
                const int row = l4 * 4 + i;
                const int byte = (row * 128 + (tc * 16 + l15) * 4) ^ ((row & 7) << 4);
                *(float*)(hw + byte) = fmaxf(a[i] + bias, 0.f);
            }
        }
        // ---- transpose read-back (wave-private; lgkmcnt ordering, no barrier)
        bf16x8 Phi, Plo;
        {
            const int base = (l15 * 128 + l4 * 32);
            const int msk = (l15 & 7) << 4;
            float v[8];
            *(float4*)&v[0] = *(const float4*)(hw + (base ^ msk));
            *(float4*)&v[4] = *(const float4*)(hw + ((base + 16) ^ msk));
            #pragma unroll
            for (int jj = 0; jj < 8; ++jj) {
                ushort hb = f2bf(v[jj]);
                Phi[jj] = (short)hb;
                Plo[jj] = (short)f2bf(v[jj] - bf2f(hb));
            }
        }
        // ---- stage B: acc_o += hh @ W2_chunk
        #pragma unroll
        for (int oc = 0; oc < 8; ++oc) {
            const int fo = (oc * 64 + l) * 16;
            bf16x8 bh = *(const bf16x8*)(cb + 16384 + fo);
            bf16x8 bl = *(const bf16x8*)(cb + 24576 + fo);
            acc_o[oc] = __builtin_amdgcn_mfma_f32_16x16x32_bf16(Phi, bh, acc_o[oc], 0, 0, 0);
            acc_o[oc] = __builtin_amdgcn_mfma_f32_16x16x32_bf16(Plo, bh, acc_o[oc], 0, 0, 0);
            acc_o[oc] = __builtin_amdgcn_mfma_f32_16x16x32_bf16(Phi, bl, acc_o[oc], 0, 0, 0);
        }
        __syncthreads();                   // all waves done reading buf[cur]
        if (ch < 15) {
            char* db = (char*)buf + (cur ^ 32768);
            const int o16 = tid * 16;
            *(bf16x8*)(db + 0     + o16) = st[0];
            *(bf16x8*)(db + 8192  + o16) = st[1];
            *(bf16x8*)(db + 16384 + o16) = st[2];
            *(bf16x8*)(db + 24576 + o16) = st[3];
            __syncthreads();               // next buffer visible
            cur ^= 32768;
        }
    }
    // ---- epilogue: + b2 + residual
    #pragma unroll
    for (int oc = 0; oc < 8; ++oc) {
        const int col = oc * 16 + l15;
        const float b2v = b2[col];
        #pragma unroll
        for (int i = 0; i < 4; ++i) {
            const int node = nbase + w * 16 + l4 * 4 + i;
            if (node < n)
                out[(size_t)node * DD + col] = acc_o[oc][i] + b2v + nf1[(size_t)node * DD + col];
        }
    }
}

extern "C" void kernel_launch(void* const* d_in, const int* in_sizes, int n_in,
                              void* d_out, int out_size, void* d_ws, size_t ws_size,
                              hipStream_t stream) {
    const float* nf       = (const float*)d_in[0];
    const int*   ei       = (const int*)d_in[1];
    const float* ln1_g    = (const float*)d_in[2];
    const float* ln1_b    = (const float*)d_in[3];
    const float* W_att    = (const float*)d_in[4];
    const float* att_src  = (const float*)d_in[5];
    const float* att_dst  = (const float*)d_in[6];
    const float* bias_att = (const float*)d_in[7];
    const float* ln2_g    = (const float*)d_in[8];
    const float* ln2_b    = (const float*)d_in[9];
    const float* W1       = (const float*)d_in[10];
    const float* b1       = (const float*)d_in[11];
    const float* W2       = (const float*)d_in[12];
    const float* b2       = (const float*)d_in[13];
    const int n = in_sizes[0] / DD;
    const int E = in_sizes[1] / 2;

    char* ws = (char*)d_ws;
    size_t off = 0;
    auto alloc = [&](size_t bytes) {
        off = (off + 255) & ~(size_t)255;
        char* p = ws + off;
        off += bytes;
        return p;
    };
    ushort* xb      = (ushort*)alloc((size_t)n * DD * 2);    // bf16 message payload
    float*  a_s     = (float*)alloc((size_t)n * HH * 4);
    float*  a_d     = (float*)alloc((size_t)n * HH * 4);
    float*  nf1     = (float*)alloc((size_t)n * DD * 4);
    float*  h2      = (float*)alloc((size_t)n * DD * 4);
    int*    row_ptr = (int*)alloc((size_t)(n + 1) * 4);
    int*    cursor  = (int*)alloc((size_t)n * 4);
    int*    deg     = (int*)alloc((size_t)n * 4);
    int*    incl    = (int*)alloc((size_t)n * 4);
    int*    bsum    = (int*)alloc(64 * 4);
    int*    col_src = (int*)alloc((size_t)E * 4);
    ushort* WAhi    = (ushort*)alloc((size_t)144 * DD * 2);   // [W_att^T | Was | Wad] (Was/Wad log2e-scaled)
    ushort* WAlo    = (ushort*)alloc((size_t)144 * DD * 2);
    ushort* W1Fhi   = (ushort*)alloc((size_t)DFF * DD * 2);   // frag-order planes
    ushort* W1Flo   = (ushort*)alloc((size_t)DFF * DD * 2);
    ushort* W2Fhi   = (ushort*)alloc((size_t)DD * DFF * 2);
    ushort* W2Flo   = (ushort*)alloc((size_t)DD * DFF * 2);
    (void)ws_size; (void)n_in; (void)out_size;

    const int nb3   = (n + 4095) / 4096;
    const int nblk1 = (n + TM - 1) / TM;                  // k1 blocks
    const int nblk2 = (E + 255) / 256;                    // k2 blocks
    const int nblk0 = 81 + (n + 255) / 256;               // prep blocks

    p0_prep<<<nblk0, 256, 0, stream>>>(W_att, att_src, att_dst, W1, W2,
                                       WAhi, WAlo, W1Fhi, W1Flo, W2Fhi, W2Flo, deg, n);
    p1_ln_deg<<<nblk1 + nblk2, 256, 0, stream>>>(nf, ln1_g, ln1_b, WAhi, WAlo,
                                                 xb, a_s, a_d, ei, deg, n, E, nblk1);
    k3a<<<nb3, 1024, 0, stream>>>(deg, incl, bsum, n);
    k3c<<<(n + 255) / 256, 256, 0, stream>>>(incl, bsum, deg, row_ptr, cursor, n);
    k4_scatter<<<nblk2, 256, 0, stream>>>(ei, cursor, col_src, E);
    k5_gather<<<(n + 3) / 4, 256, 0, stream>>>(xb, a_s, a_d, row_ptr, col_src, nf, bias_att,
                                               ln2_g, ln2_b, nf1, h2, n);
    k6_mfma<<<(n + TM6 - 1) / TM6, 512, 0, stream>>>(h2, nf1, W1Fhi, W1Flo, W2Fhi, W2Flo,
                                                     b1, b2, (float*)d_out, n);
}

// Round 9
// 322.032 us; speedup vs baseline: 1.7823x; 1.0246x over previous
//
#include <hip/hip_runtime.h>

#define DD 128
#define HH 8
#define DFF 512
#define EPS 1e-6f
#define SLOPE 0.2f
#define LOG2E 1.4426950408889634f
#define TM 64
#define TM6 128

typedef float f32x4 __attribute__((ext_vector_type(4)));
typedef short bf16x8 __attribute__((ext_vector_type(8)));

__device__ __forceinline__ ushort f2bf(float f) {
    unsigned u = __float_as_uint(f);
    return (ushort)((u + 0x7FFFu + ((u >> 16) & 1u)) >> 16);   // RNE
}
__device__ __forceinline__ float bf2f(ushort h) {
    return __uint_as_float(((unsigned)h) << 16);
}

// async global->LDS: per-lane global src, wave-uniform LDS base (+lane*16 by HW)
__device__ __forceinline__ void g2lds16(const ushort* gsrc, ushort* ldst) {
    __builtin_amdgcn_global_load_lds(
        (const __attribute__((address_space(1))) unsigned int*)gsrc,
        (__attribute__((address_space(3))) unsigned int*)ldst, 16, 0, 0);
}

// ================= P0: fused prep (kzero | ksplitT(W_att) | kattw | kfrag1 | kfrag2) ==========
__device__ void d_splitT(int bp, int tid, const float* __restrict__ src,
                         ushort* __restrict__ hi, ushort* __restrict__ lo, int R, int C) {
    __shared__ float tile[32][33];
    const int tc = (bp & 3) * 32, tr = (bp >> 2) * 32;
    const int lx = tid & 31, ly = tid >> 5;            // 32 x 8
    for (int i = 0; i < 32; i += 8) {
        int r = tr + ly + i, c = tc + lx;
        tile[ly + i][lx] = (r < R && c < C) ? src[(size_t)r * C + c] : 0.f;
    }
    __syncthreads();
    for (int i = 0; i < 32; i += 8) {
        int c = tc + ly + i, r = tr + lx;
        if (c < C && r < R) {
            float f = tile[lx][ly + i];
            ushort h = f2bf(f);
            hi[(size_t)c * R + r] = h;
            lo[(size_t)c * R + r] = f2bf(f - bf2f(h));
        }
    }
}

__device__ void d_attw(int tid, const float* __restrict__ W, const float* __restrict__ asrc,
                       const float* __restrict__ adst, ushort* __restrict__ hi,
                       ushort* __restrict__ lo) {
    if (tid >= DD) return;
    const int k = tid;
    for (int h = 0; h < HH; ++h) {
        float s1 = 0.f, s2 = 0.f;
        #pragma unroll
        for (int dh = 0; dh < 16; ++dh) {
            float w = W[k * DD + h * 16 + dh];
            s1 = fmaf(w, asrc[h * 16 + dh], s1);
            s2 = fmaf(w, adst[h * 16 + dh], s2);
        }
        s1 *= LOG2E;   // fold log2e: k5 softmax runs in exp2 domain
        s2 *= LOG2E;
        ushort h1 = f2bf(s1);
        hi[(128 + h) * DD + k] = h1;
        lo[(128 + h) * DD + k] = f2bf(s1 - bf2f(h1));
        ushort h2 = f2bf(s2);
        hi[(136 + h) * DD + k] = h2;
        lo[(136 + h) * DD + k] = f2bf(s2 - bf2f(h2));
    }
}

__device__ void d_frag1(int bp, int tid, const float* __restrict__ W1,
                        ushort* __restrict__ hi, ushort* __restrict__ lo) {
    const int f = bp * 256 + tid;                      // 8192 frags
    const int l = f & 63, s = (f >> 6) & 3, tc = (f >> 8) & 1, ch = f >> 9;
    const int ff = ch * 32 + tc * 16 + (l & 15);
    const int k0 = s * 32 + (l >> 4) * 8;
    #pragma unroll
    for (int j = 0; j < 8; ++j) {
        float w = W1[(size_t)(k0 + j) * DFF + ff];
        ushort h = f2bf(w);
        hi[f * 8 + j] = h;
        lo[f * 8 + j] = f2bf(w - bf2f(h));
    }
}

__device__ void d_frag2(int bp, int tid, const float* __restrict__ W2,
                        ushort* __restrict__ hi, ushort* __restrict__ lo) {
    const int f = bp * 256 + tid;                      // 8192 frags
    const int l = f & 63, oc = (f >> 6) & 7, ch = f >> 9;
    const int out = oc * 16 + (l & 15);
    const int k0 = ch * 32 + (l >> 4) * 8;
    #pragma unroll
    for (int j = 0; j < 8; ++j) {
        float w = W2[(size_t)(k0 + j) * DD + out];
        ushort h = f2bf(w);
        hi[f * 8 + j] = h;
        lo[f * 8 + j] = f2bf(w - bf2f(h));
    }
}

__global__ __launch_bounds__(256) void p0_prep(
    const float* __restrict__ W_att, const float* __restrict__ asrc,
    const float* __restrict__ adst, const float* __restrict__ W1, const float* __restrict__ W2,
    ushort* __restrict__ WAhi, ushort* __restrict__ WAlo,
    ushort* __restrict__ W1Fhi, ushort* __restrict__ W1Flo,
    ushort* __restrict__ W2Fhi, ushort* __restrict__ W2Flo,
    int* __restrict__ deg, int n) {
    const int bp = blockIdx.x, tid = threadIdx.x;
    if (bp < 16)            d_splitT(bp, tid, W_att, WAhi, WAlo, DD, DD);
    else if (bp == 16)      d_attw(tid, W_att, asrc, adst, WAhi, WAlo);
    else if (bp < 49)       d_frag1(bp - 17, tid, W1, W1Fhi, W1Flo);
    else if (bp < 81)       d_frag2(bp - 49, tid, W2, W2Fhi, W2Flo);
    else {
        int i = (bp - 81) * 256 + tid;
        if (i < n) deg[i] = 0;
    }
}

// ================= P1: fused k1_mfma | k2_deg (independent work, concurrent) =================
__device__ void d_k1(int bid, int tid,
                     const float* __restrict__ nf, const float* __restrict__ g,
                     const float* __restrict__ b, const ushort* __restrict__ WAhi,
                     const ushort* __restrict__ WAlo, ushort* __restrict__ xb,
                     float* __restrict__ a_s, float* __restrict__ a_d, int n) {
    const int w = tid >> 6, l = tid & 63;
    const int l15 = l & 15, l4 = l >> 4;
    const int nbase = bid * TM;
    int arow = nbase + w * 16 + l15;
    if (arow >= n) arow = n - 1;

    float v[4][8];
    const float* ap = nf + (size_t)arow * DD + l4 * 8;
    #pragma unroll
    for (int s = 0; s < 4; ++s) {
        *(float4*)&v[s][0] = *(const float4*)(ap + s * 32);
        *(float4*)&v[s][4] = *(const float4*)(ap + s * 32 + 4);
    }
    float sum = 0.f;
    #pragma unroll
    for (int s = 0; s < 4; ++s)
        #pragma unroll
        for (int j = 0; j < 8; ++j) sum += v[s][j];
    sum += __shfl_xor(sum, 16);
    sum += __shfl_xor(sum, 32);
    const float mean = sum * (1.f / DD);
    float qs = 0.f;
    #pragma unroll
    for (int s = 0; s < 4; ++s)
        #pragma unroll
        for (int j = 0; j < 8; ++j) { float d = v[s][j] - mean; qs += d * d; }
    qs += __shfl_xor(qs, 16);
    qs += __shfl_xor(qs, 32);
    const float iv = 1.f / (sqrtf(qs * (1.f / (DD - 1))) + EPS);

    bf16x8 Ahi[4], Alo[4];
    #pragma unroll
    for (int s = 0; s < 4; ++s) {
        const int k0 = s * 32 + l4 * 8;
        float gv[8], bv[8];
        *(float4*)&gv[0] = *(const float4*)(g + k0);
        *(float4*)&gv[4] = *(const float4*)(g + k0 + 4);
        *(float4*)&bv[0] = *(const float4*)(b + k0);
        *(float4*)&bv[4] = *(const float4*)(b + k0 + 4);
        bf16x8 hv, lv;
        #pragma unroll
        for (int j = 0; j < 8; ++j) {
            float f = fmaf(gv[j], (v[s][j] - mean) * iv, bv[j]);
            ushort hb = f2bf(f);
            hv[j] = (short)hb;
            lv[j] = (short)f2bf(f - bf2f(hb));
        }
        Ahi[s] = hv; Alo[s] = lv;
    }

    #pragma unroll
    for (int oc = 0; oc < 9; ++oc) {
        f32x4 acc = (f32x4){0.f, 0.f, 0.f, 0.f};
        const ushort* bp = WAhi + (size_t)(oc * 16 + l15) * DD + l4 * 8;
        const ushort* lp = WAlo + (size_t)(oc * 16 + l15) * DD + l4 * 8;
        #pragma unroll
        for (int s = 0; s < 4; ++s) {
            bf16x8 bh = *(const bf16x8*)(bp + s * 32);
            bf16x8 bl = *(const bf16x8*)(lp + s * 32);
            acc = __builtin_amdgcn_mfma_f32_16x16x32_bf16(Ahi[s], bh, acc, 0, 0, 0);
            acc = __builtin_amdgcn_mfma_f32_16x16x32_bf16(Alo[s], bh, acc, 0, 0, 0);
            acc = __builtin_amdgcn_mfma_f32_16x16x32_bf16(Ahi[s], bl, acc, 0, 0, 0);
        }
        #pragma unroll
        for (int i = 0; i < 4; ++i) {
            const int node = nbase + w * 16 + l4 * 4 + i;
            if (node < n) {
                if (oc < 8) xb[(size_t)node * DD + oc * 16 + l15] = f2bf(acc[i]);
                else if (l15 < 8) a_s[node * HH + l15] = acc[i];
                else a_d[node * HH + (l15 - 8)] = acc[i];
            }
        }
    }
}

__global__ __launch_bounds__(256) void p1_ln_deg(
    const float* __restrict__ nf, const float* __restrict__ g, const float* __restrict__ b,
    const ushort* __restrict__ WAhi, const ushort* __restrict__ WAlo,
    ushort* __restrict__ xb, float* __restrict__ a_s, float* __restrict__ a_d,
    const int* __restrict__ ei, int* __restrict__ deg, int n, int E, int nblk1) {
    const int bp = blockIdx.x;
    if (bp < nblk1) {
        d_k1(bp, threadIdx.x, nf, g, b, WAhi, WAlo, xb, a_s, a_d, n);
    } else {
        int e = (bp - nblk1) * 256 + threadIdx.x;
        if (e < E) atomicAdd(&deg[ei[E + e]], 1);
    }
}

// ---------------- K3a: per-4096-block inclusive scan + block totals ----------------
__global__ __launch_bounds__(1024) void k3a(const int* __restrict__ deg, int* __restrict__ incl,
                                            int* __restrict__ bsum, int n) {
    __shared__ int wsum[16];
    const int b = blockIdx.x, t = threadIdx.x;
    const int i0 = b * 4096 + t * 4;
    int4 v = make_int4(0, 0, 0, 0);
    if (i0 + 3 < n) v = *(const int4*)&deg[i0];
    else {
        int* vp = (int*)&v;
        for (int q = 0; q < 4; ++q) vp[q] = (i0 + q < n) ? deg[i0 + q] : 0;
    }
    const int s1 = v.x, s2 = s1 + v.y, s3 = s2 + v.z, s4 = s3 + v.w;
    const int lane = t & 63, wv = t >> 6;
    int xx = s4;
    #pragma unroll
    for (int off = 1; off < 64; off <<= 1) {
        int y = __shfl_up(xx, off);
        if (lane >= off) xx += y;
    }
    if (lane == 63) wsum[wv] = xx;
    __syncthreads();
    if (wv == 0) {
        int y = (lane < 16) ? wsum[lane] : 0;
        #pragma unroll
        for (int off = 1; off < 16; off <<= 1) {
            int z = __shfl_up(y, off);
            if (lane >= off) y += z;
        }
        if (lane < 16) wsum[lane] = y;
    }
    __syncthreads();
    const int wbase = (wv == 0) ? 0 : wsum[wv - 1];
    const int excl = xx - s4 + wbase;
    if (i0 < n) {
        int4 o = make_int4(excl + s1, excl + s2, excl + s3, excl + s4);
        if (i0 + 3 < n) *(int4*)&incl[i0] = o;
        else {
            int* op = (int*)&o;
            for (int q = 0; q < 4; ++q) if (i0 + q < n) incl[i0 + q] = op[q];
        }
    }
    if (t == 1023) bsum[b] = wbase + xx;
}

// ---------------- K3c: finalize row_ptr/cursor, inline 13-entry bsum scan ----------------
__global__ void k3c(const int* __restrict__ incl, const int* __restrict__ bsum,
                    const int* __restrict__ deg, int* __restrict__ row_ptr,
                    int* __restrict__ cursor, int n) {
    int i = blockIdx.x * blockDim.x + threadIdx.x;
    if (i < n) {
        int b = i >> 12;
        int base = 0;
        for (int q = 0; q < b; ++q) base += bsum[q];   // b <= 12, L2-hot
        int inc = incl[i] + base;
        row_ptr[i + 1] = inc;
        cursor[i] = inc - deg[i];
        if (i == 0) row_ptr[0] = 0;
    }
}

// ---------------- K4: scatter src ids into CSR ----------------
__global__ void k4_scatter(const int* __restrict__ ei, int* __restrict__ cursor,
                           int* __restrict__ col_src, int E) {
    int e = blockIdx.x * blockDim.x + threadIdx.x;
    if (e < E) {
        int dst = ei[E + e];
        int pos = atomicAdd(&cursor[dst], 1);
        col_src[pos] = ei[e];
    }
}

// ---------------- K5: per-dst online-softmax gather (bf16 payload, exp2 domain) ----------------
__global__ __launch_bounds__(256) void k5_gather(
    const ushort* __restrict__ xb, const float* __restrict__ a_s, const float* __restrict__ a_d,
    const int* __restrict__ row_ptr, const int* __restrict__ col_src,
    const float* __restrict__ nf, const float* __restrict__ bias_att,
    const float* __restrict__ ln2g, const float* __restrict__ ln2b,
    float* __restrict__ nf1, float* __restrict__ h2, int n) {
    const int w = (blockIdx.x * blockDim.x + threadIdx.x) >> 6;
    if (w >= n) return;
    const int lane = threadIdx.x & 63;
    const int h = lane >> 3;
    const int c0 = lane * 2;
    const float ad = a_d[w * HH + h];
    float e = a_s[w * HH + h] + ad;      // already log2e-scaled (prep fold)
    e = e > 0.f ? e : SLOPE * e;
    float m = e, denom = 1.f;
    const uint xw = *(const uint*)&xb[(size_t)w * DD + c0];
    float acc0 = __uint_as_float(xw << 16);
    float acc1 = __uint_as_float(xw & 0xFFFF0000u);
    const int beg = row_ptr[w], end = row_ptr[w + 1];
    int j = beg;
    const int j4end = beg + ((end - beg) & ~3);

#define BATCH_MATH(F0, F1, F2, F3, U0, U1, U2, U3) {                                   \
        float f0 = (F0) + ad, f1 = (F1) + ad, f2 = (F2) + ad, f3 = (F3) + ad;          \
        f0 = f0 > 0.f ? f0 : SLOPE * f0;  f1 = f1 > 0.f ? f1 : SLOPE * f1;             \
        f2 = f2 > 0.f ? f2 : SLOPE * f2;  f3 = f3 > 0.f ? f3 : SLOPE * f3;             \
        const float mb = fmaxf(fmaxf(f0, f1), fmaxf(f2, f3));                          \
        const float nm = fmaxf(m, mb);                                                 \
        const float sc = exp2f(m - nm);                                                \
        const float p0 = exp2f(f0 - nm), p1 = exp2f(f1 - nm);                          \
        const float p2 = exp2f(f2 - nm), p3 = exp2f(f3 - nm);                          \
        denom = denom * sc + ((p0 + p1) + (p2 + p3));                                  \
        acc0 = acc0 * sc + (fmaf(__uint_as_float((U0) << 16), p0,                      \
                                 __uint_as_float((U1) << 16) * p1)                     \
                          + fmaf(__uint_as_float((U2) << 16), p2,                      \
                                 __uint_as_float((U3) << 16) * p3));                   \
        acc1 = acc1 * sc + (fmaf(__uint_as_float((U0) & 0xFFFF0000u), p0,              \
                                 __uint_as_float((U1) & 0xFFFF0000u) * p1)             \
                          + fmaf(__uint_as_float((U2) & 0xFFFF0000u), p2,              \
                                 __uint_as_float((U3) & 0xFFFF0000u) * p3));           \
        m = nm; }

    if (j < j4end) {
        int s0 = col_src[j], s1 = col_src[j + 1], s2 = col_src[j + 2], s3 = col_src[j + 3];
        float e0 = a_s[s0 * HH + h], e1 = a_s[s1 * HH + h];
        float e2 = a_s[s2 * HH + h], e3 = a_s[s3 * HH + h];
        uint x0 = *(const uint*)&xb[(size_t)s0 * DD + c0];
        uint x1 = *(const uint*)&xb[(size_t)s1 * DD + c0];
        uint x2 = *(const uint*)&xb[(size_t)s2 * DD + c0];
        uint x3 = *(const uint*)&xb[(size_t)s3 * DD + c0];
        for (j += 4;; j += 4) {
            const bool more = j < j4end;
            float ne0, ne1, ne2, ne3;
            uint nx0, nx1, nx2, nx3;
            if (more) {   // issue next-batch loads before current-batch math
                const int t0 = col_src[j], t1 = col_src[j + 1];
                const int t2 = col_src[j + 2], t3 = col_src[j + 3];
                ne0 = a_s[t0 * HH + h]; ne1 = a_s[t1 * HH + h];
                ne2 = a_s[t2 * HH + h]; ne3 = a_s[t3 * HH + h];
                nx0 = *(const uint*)&xb[(size_t)t0 * DD + c0];
                nx1 = *(const uint*)&xb[(size_t)t1 * DD + c0];
                nx2 = *(const uint*)&xb[(size_t)t2 * DD + c0];
                nx3 = *(const uint*)&xb[(size_t)t3 * DD + c0];
            }
            BATCH_MATH(e0, e1, e2, e3, x0, x1, x2, x3)
            if (!more) break;
            e0 = ne0; e1 = ne1; e2 = ne2; e3 = ne3;
            x0 = nx0; x1 = nx1; x2 = nx2; x3 = nx3;
        }
    }
    for (; j < end; ++j) {
        const int s0 = col_src[j];
        float ev = a_s[s0 * HH + h] + ad;
        ev = ev > 0.f ? ev : SLOPE * ev;
        const uint x0 = *(const uint*)&xb[(size_t)s0 * DD + c0];
        const float nm = fmaxf(m, ev);
        const float sc = exp2f(m - nm);
        const float pp = exp2f(ev - nm);
        denom = denom * sc + pp;
        acc0 = acc0 * sc + __uint_as_float(x0 << 16) * pp;
        acc1 = acc1 * sc + __uint_as_float(x0 & 0xFFFF0000u) * pp;
        m = nm;
    }
#undef BATCH_MATH
    const float inv = 1.f / (denom + 1e-16f);
    float o0 = acc0 * inv + bias_att[c0]     + nf[(size_t)w * DD + c0];
    float o1 = acc1 * inv + bias_att[c0 + 1] + nf[(size_t)w * DD + c0 + 1];
    *(float2*)&nf1[(size_t)w * DD + c0] = make_float2(o0, o1);
    float s = o0 + o1;
    #pragma unroll
    for (int o = 32; o >= 1; o >>= 1) s += __shfl_xor(s, o);
    const float mean = s * (1.f / DD);
    const float d0 = o0 - mean, d1 = o1 - mean;
    float q = d0 * d0 + d1 * d1;
    #pragma unroll
    for (int o = 32; o >= 1; o >>= 1) q += __shfl_xor(q, o);
    const float var = q * (1.f / (DD - 1));
    const float iv = 1.f / (sqrtf(var) + EPS);
    float z0 = ln2g[c0] * d0 * iv + ln2b[c0];
    float z1 = ln2g[c0 + 1] * d1 * iv + ln2b[c0 + 1];
    *(float2*)&h2[(size_t)w * DD + c0] = make_float2(z0, z1);
}

// ---------------- K6: split-bf16 MFMA FFN, async global_load_lds dbuf, 1 barrier/chunk ------
// Frag-order weights => staging is linear: LDS dst = wave-uniform base + lane*16 (the exact
// global_load_lds contract). Issue next-chunk DMA at chunk start into buf[cur^1]; the single
// __syncthreads() at chunk end drains vmcnt(0) (completion guarantee) and publishes the buffer.
__global__ __launch_bounds__(512, 4) void k6_mfma(
    const float* __restrict__ h2, const float* __restrict__ nf1,
    const ushort* __restrict__ W1Fhi, const ushort* __restrict__ W1Flo,
    const ushort* __restrict__ W2Fhi, const ushort* __restrict__ W2Flo,
    const float* __restrict__ b1, const float* __restrict__ b2,
    float* __restrict__ out, int n) {
    __shared__ ushort buf[2][16384];   // 64KB: [W1hi 8KB | W1lo 8KB | W2hi 8KB | W2lo 8KB] x2
    __shared__ float hhs[4096];        // 16KB: 8 waves x [16 nodes][32 ff] swizzled
    const int tid = threadIdx.x;
    const int w = tid >> 6, l = tid & 63;
    const int l15 = l & 15, l4 = l >> 4;
    const int nbase = blockIdx.x * TM6;
    char* hw = (char*)hhs + w * 2048;
    // per-wave staging bases: LDS uniform offset w*1024 bytes; global ushort offset w*512 + l*8
    const int wg = w * 512 + l * 8;          // per-lane global ushort offset within a plane-chunk
    ushort* lb0 = (ushort*)((char*)buf + w * 1024);   // wave-uniform LDS base, plane stride 8192B

    // ---- A-frags: this wave's 16 node rows of h2, split into hi/lo bf16
    int arow = nbase + w * 16 + l15;
    if (arow >= n) arow = n - 1;                    // clamp; tail writes guarded
    const float* ap = h2 + (size_t)arow * DD + l4 * 8;
    bf16x8 Ahi[4], Alo[4];
    #pragma unroll
    for (int s = 0; s < 4; ++s) {
        float v[8];
        *(float4*)&v[0] = *(const float4*)(ap + s * 32);
        *(float4*)&v[4] = *(const float4*)(ap + s * 32 + 4);
        bf16x8 hv, lv;
        #pragma unroll
        for (int jj = 0; jj < 8; ++jj) {
            ushort hb = f2bf(v[jj]);
            hv[jj] = (short)hb;
            lv[jj] = (short)f2bf(v[jj] - bf2f(hb));
        }
        Ahi[s] = hv; Alo[s] = lv;
    }

    f32x4 acc_o[8];
    #pragma unroll
    for (int oc = 0; oc < 8; ++oc) acc_o[oc] = (f32x4){0.f, 0.f, 0.f, 0.f};

    // ---- prologue: async-stage chunk 0 into buf[0]
    g2lds16(W1Fhi + wg, lb0);
    g2lds16(W1Flo + wg, (ushort*)((char*)lb0 + 8192));
    g2lds16(W2Fhi + wg, (ushort*)((char*)lb0 + 16384));
    g2lds16(W2Flo + wg, (ushort*)((char*)lb0 + 24576));
    __syncthreads();                                  // vmcnt(0) drain + publish

    int cur = 0;
    #pragma unroll 1
    for (int ch = 0; ch < 16; ++ch) {
        // ---- issue next-chunk DMA into the other buffer (consumed after the barrier)
        if (ch < 15) {
            const int go = (ch + 1) * 4096 + wg;
            ushort* lb = (ushort*)((char*)lb0 + (cur ^ 32768));
            g2lds16(W1Fhi + go, lb);
            g2lds16(W1Flo + go, (ushort*)((char*)lb + 8192));
            g2lds16(W2Fhi + go, (ushort*)((char*)lb + 16384));
            g2lds16(W2Flo + go, (ushort*)((char*)lb + 24576));
        }
        const char* cb = (const char*)buf + cur;
        // ---- stage A: hh[16 nodes][32 ff] = relu(h2 @ W1_chunk + b1)
        #pragma unroll
        for (int tc = 0; tc < 2; ++tc) {
            f32x4 a = (f32x4){0.f, 0.f, 0.f, 0.f};
            #pragma unroll
            for (int s = 0; s < 4; ++s) {
                const int fo = ((tc * 4 + s) * 64 + l) * 16;
                bf16x8 bh = *(const bf16x8*)(cb + fo);
                bf16x8 bl = *(const bf16x8*)(cb + 8192 + fo);
                a = __builtin_amdgcn_mfma_f32_16x16x32_bf16(Ahi[s], bh, a, 0, 0, 0);
                a = __builtin_amdgcn_mfma_f32_16x16x32_bf16(Alo[s], bh, a, 0, 0, 0);
                a = __builtin_amdgcn_mfma_f32_16x16x32_bf16(Ahi[s], bl, a, 0, 0, 0);
            }
            const float bias = b1[ch * 32 + tc * 16 + l15];
            #pragma unroll
            for (int i = 0; i < 4; ++i) {
                const int row = l4 * 4 + i;
                const int byte = (row * 128 + (tc * 16 + l15) * 4) ^ ((row & 7) << 4);
                *(float*)(hw + byte) = fmaxf(a[i] + bias, 0.f);
            }
        }
        // ---- transpose read-back (wave-private; lgkmcnt ordering, no barrier)
        bf16x8 Phi, Plo;
        {
            const int base = (l15 * 128 + l4 * 32);
            const int msk = (l15 & 7) << 4;
            float v[8];
            *(float4*)&v[0] = *(const float4*)(hw + (base ^ msk));
            *(float4*)&v[4] = *(const float4*)(hw + ((base + 16) ^ msk));
            #pragma unroll
            for (int jj = 0; jj < 8; ++jj) {
                ushort hb = f2bf(v[jj]);
                Phi[jj] = (short)hb;
                Plo[jj] = (short)f2bf(v[jj] - bf2f(hb));
            }
        }
        // ---- stage B: acc_o += hh @ W2_chunk
        #pragma unroll
        for (int oc = 0; oc < 8; ++oc) {
            const int fo = (oc * 64 + l) * 16;
            bf16x8 bh = *(const bf16x8*)(cb + 16384 + fo);
            bf16x8 bl = *(const bf16x8*)(cb + 24576 + fo);
            acc_o[oc] = __builtin_amdgcn_mfma_f32_16x16x32_bf16(Phi, bh, acc_o[oc], 0, 0, 0);
            acc_o[oc] = __builtin_amdgcn_mfma_f32_16x16x32_bf16(Plo, bh, acc_o[oc], 0, 0, 0);
            acc_o[oc] = __builtin_amdgcn_mfma_f32_16x16x32_bf16(Phi, bl, acc_o[oc], 0, 0, 0);
        }
        __syncthreads();   // readers of buf[cur] done + DMA into buf[cur^1] drained (vmcnt 0)
        cur ^= 32768;
    }
    // ---- epilogue: + b2 + residual
    #pragma unroll
    for (int oc = 0; oc < 8; ++oc) {
        const int col = oc * 16 + l15;
        const float b2v = b2[col];
        #pragma unroll
        for (int i = 0; i < 4; ++i) {
            const int node = nbase + w * 16 + l4 * 4 + i;
            if (node < n)
                out[(size_t)node * DD + col] = acc_o[oc][i] + b2v + nf1[(size_t)node * DD + col];
        }
    }
}

extern "C" void kernel_launch(void* const* d_in, const int* in_sizes, int n_in,
                              void* d_out, int out_size, void* d_ws, size_t ws_size,
                              hipStream_t stream) {
    const float* nf       = (const float*)d_in[0];
    const int*   ei       = (const int*)d_in[1];
    const float* ln1_g    = (const float*)d_in[2];
    const float* ln1_b    = (const float*)d_in[3];
    const float* W_att    = (const float*)d_in[4];
    const float* att_src  = (const float*)d_in[5];
    const float* att_dst  = (const float*)d_in[6];
    const float* bias_att = (const float*)d_in[7];
    const float* ln2_g    = (const float*)d_in[8];
    const float* ln2_b    = (const float*)d_in[9];
    const float* W1       = (const float*)d_in[10];
    const float* b1       = (const float*)d_in[11];
    const float* W2       = (const float*)d_in[12];
    const float* b2       = (const float*)d_in[13];
    const int n = in_sizes[0] / DD;
    const int E = in_sizes[1] / 2;

    char* ws = (char*)d_ws;
    size_t off = 0;
    auto alloc = [&](size_t bytes) {
        off = (off + 255) & ~(size_t)255;
        char* p = ws + off;
        off += bytes;
        return p;
    };
    ushort* xb      = (ushort*)alloc((size_t)n * DD * 2);    // bf16 message payload
    float*  a_s     = (float*)alloc((size_t)n * HH * 4);
    float*  a_d     = (float*)alloc((size_t)n * HH * 4);
    float*  nf1     = (float*)alloc((size_t)n * DD * 4);
    float*  h2      = (float*)alloc((size_t)n * DD * 4);
    int*    row_ptr = (int*)alloc((size_t)(n + 1) * 4);
    int*    cursor  = (int*)alloc((size_t)n * 4);
    int*    deg     = (int*)alloc((size_t)n * 4);
    int*    incl    = (int*)alloc((size_t)n * 4);
    int*    bsum    = (int*)alloc(64 * 4);
    int*    col_src = (int*)alloc((size_t)E * 4);
    ushort* WAhi    = (ushort*)alloc((size_t)144 * DD * 2);   // [W_att^T | Was | Wad] (log2e-scaled)
    ushort* WAlo    = (ushort*)alloc((size_t)144 * DD * 2);
    ushort* W1Fhi   = (ushort*)alloc((size_t)DFF * DD * 2);   // frag-order planes
    ushort* W1Flo   = (ushort*)alloc((size_t)DFF * DD * 2);
    ushort* W2Fhi   = (ushort*)alloc((size_t)DD * DFF * 2);
    ushort* W2Flo   = (ushort*)alloc((size_t)DD * DFF * 2);
    (void)ws_size; (void)n_in; (void)out_size;

    const int nb3   = (n + 4095) / 4096;
    const int nblk1 = (n + TM - 1) / TM;                  // k1 blocks
    const int nblk2 = (E + 255) / 256;                    // k2 blocks
    const int nblk0 = 81 + (n + 255) / 256;               // prep blocks

    p0_prep<<<nblk0, 256, 0, stream>>>(W_att, att_src, att_dst, W1, W2,
                                       WAhi, WAlo, W1Fhi, W1Flo, W2Fhi, W2Flo, deg, n);
    p1_ln_deg<<<nblk1 + nblk2, 256, 0, stream>>>(nf, ln1_g, ln1_b, WAhi, WAlo,
                                                 xb, a_s, a_d, ei, deg, n, E, nblk1);
    k3a<<<nb3, 1024, 0, stream>>>(deg, incl, bsum, n);
    k3c<<<(n + 255) / 256, 256, 0, stream>>>(incl, bsum, deg, row_ptr, cursor, n);
    k4_scatter<<<nblk2, 256, 0, stream>>>(ei, cursor, col_src, E);
    k5_gather<<<(n + 3) / 4, 256, 0, stream>>>(xb, a_s, a_d, row_ptr, col_src, nf, bias_att,
                                               ln2_g, ln2_b, nf1, h2, n);
    k6_mfma<<<(n + TM6 - 1) / TM6, 512, 0, stream>>>(h2, nf1, W1Fhi, W1Flo, W2Fhi, W2Flo,
                                                     b1, b2, (float*)d_out, n);
}